// Round 3
// baseline (377.622 us; speedup 1.0000x reference)
//
#include <hip/hip_runtime.h>
#include <stdint.h>

#define DEV static __device__ __forceinline__

typedef __bf16 bf16_t;
typedef bf16_t bf16x8 __attribute__((ext_vector_type(8)));
typedef bf16_t bf16x4 __attribute__((ext_vector_type(4)));
typedef float f32x4 __attribute__((ext_vector_type(4)));

static constexpr int Bc = 4, Sc = 2048, Dc = 1024, Hc = 16, DKc = 64;
static constexpr int Mrows = Bc * Sc; // 8192

DEV unsigned short f2bf(float f) {
  unsigned int u = __float_as_uint(f);
  u += 0x7fffu + ((u >> 16) & 1u);
  return (unsigned short)(u >> 16);
}

DEV float fexp2(float x) {
#if __has_builtin(__builtin_amdgcn_exp2f)
  return __builtin_amdgcn_exp2f(x); // single v_exp_f32
#else
  return exp2f(x);
#endif
}

// 16x16x16 bf16 MFMA (K=16): A-frag k-granularity = lhi*4 -- matches the
// swapped-QK^T D-layout exactly, so P feeds PV straight from registers.
#if __has_builtin(__builtin_amdgcn_mfma_f32_16x16x16_bf16)
DEV f32x4 mfma16(bf16x4 a, bf16x4 b, f32x4 c) {
  return __builtin_amdgcn_mfma_f32_16x16x16_bf16(a, b, c, 0, 0, 0);
}
#elif __has_builtin(__builtin_amdgcn_mfma_f32_16x16x16bf16_1k)
typedef short s16x4 __attribute__((ext_vector_type(4)));
DEV f32x4 mfma16(bf16x4 a, bf16x4 b, f32x4 c) {
  union U { bf16x4 h; s16x4 s; };
  U ua, ub; ua.h = a; ub.h = b;
  return __builtin_amdgcn_mfma_f32_16x16x16bf16_1k(ua.s, ub.s, c, 0, 0, 0);
}
#else
DEV f32x4 mfma16(bf16x4 a, bf16x4 b, f32x4 c) {
  asm("v_mfma_f32_16x16x16_bf16 %0, %1, %2, %0" : "+v"(c) : "v"(a), "v"(b));
  return c;
}
#endif

DEV void gload_lds16(const void* g, void* l) {
  __builtin_amdgcn_global_load_lds(
      (const __attribute__((address_space(1))) void*)g,
      (__attribute__((address_space(3))) void*)l, 16, 0, 0);
}

// ---------------- fp32 -> bf16 conversion (segmented: up to 4 tensors) ------
// Outputs are contiguous in workspace; segment = i >> lg (lg = log2 of per-
// tensor float4 count). One launch replaces 3-4 separate cvt launches.
__global__ void __launch_bounds__(256) cvt_bf16_seg_kernel(
    const float* __restrict__ s0, const float* __restrict__ s1,
    const float* __restrict__ s2, const float* __restrict__ s3,
    unsigned short* __restrict__ out, int lg) {
  int i = blockIdx.x * blockDim.x + threadIdx.x;
  int seg = i >> lg, j = i & ((1 << lg) - 1);
  const float* src = seg == 0 ? s0 : seg == 1 ? s1 : seg == 2 ? s2 : s3;
  float4 v = reinterpret_cast<const float4*>(src)[j];
  ushort4 o;
  o.x = f2bf(v.x); o.y = f2bf(v.y); o.z = f2bf(v.z); o.w = f2bf(v.w);
  reinterpret_cast<ushort4*>(out)[i] = o;
}

// ---------------- GEMM: C[m][n] = (sum_k A[m][k]*W[n][k] + bias[n]) * scale ----
// A: [M][K] bf16 row-major, W: [N][K] bf16 row-major (i.e. X @ W^T)
// 128x128 tile, BK=32, 256 threads (4 waves, 2x2), 4x4 16x16x32 MFMA per wave.
// MODE: 0 = f32 linear out, 1 = bf16 linear out,
//       2 = bf16 TRANSPOSED out: Cout[(b*Dc + n)*Sc + s], m = b*Sc + s
template <int MODE>
__global__ void __launch_bounds__(256) gemm_bt_kernel(
    const unsigned short* __restrict__ A, const unsigned short* __restrict__ W,
    const float* __restrict__ bias, void* __restrict__ Cout,
    int M, int N, int K, float scale) {
  __shared__ unsigned short lA[128 * 32];
  __shared__ unsigned short lB[128 * 32];
  const int t = threadIdx.x;
  const int wv = t >> 6, ln = t & 63;
  const int l15 = ln & 15, lhi = ln >> 4;
  const int m0 = blockIdx.y * 128, n0 = blockIdx.x * 128;
  const int wr = wv >> 1, wc = wv & 1;

  f32x4 acc[4][4] = {};

  for (int k0 = 0; k0 < K; k0 += 32) {
    __syncthreads();
#pragma unroll
    for (int r = 0; r < 2; ++r) {
      int e = r * 2048 + t * 8;
      int row = e >> 5, col = e & 31;
      gload_lds16(A + (size_t)(m0 + row) * K + k0 + col, (char*)lA + e * 2);
      gload_lds16(W + (size_t)(n0 + row) * K + k0 + col, (char*)lB + e * 2);
    }
    __syncthreads();
    bf16x8 af[4], bfr[4];
#pragma unroll
    for (int i = 0; i < 4; ++i)
      af[i] = *reinterpret_cast<const bf16x8*>(&lA[(wr * 64 + i * 16 + l15) * 32 + lhi * 8]);
#pragma unroll
    for (int j = 0; j < 4; ++j)
      bfr[j] = *reinterpret_cast<const bf16x8*>(&lB[(wc * 64 + j * 16 + l15) * 32 + lhi * 8]);
#pragma unroll
    for (int i = 0; i < 4; ++i)
#pragma unroll
      for (int j = 0; j < 4; ++j)
        acc[i][j] = __builtin_amdgcn_mfma_f32_16x16x32_bf16(af[i], bfr[j], acc[i][j], 0, 0, 0);
  }

#pragma unroll
  for (int i = 0; i < 4; ++i)
#pragma unroll
    for (int j = 0; j < 4; ++j) {
      int n = n0 + wc * 64 + j * 16 + l15;
      float bv = bias[n];
      if (MODE == 2) {
        int mb = m0 + wr * 64 + i * 16 + lhi * 4; // 4 consecutive m = consecutive s
        ushort4 ov;
        ov.x = f2bf((acc[i][j][0] + bv) * scale);
        ov.y = f2bf((acc[i][j][1] + bv) * scale);
        ov.z = f2bf((acc[i][j][2] + bv) * scale);
        ov.w = f2bf((acc[i][j][3] + bv) * scale);
        *reinterpret_cast<ushort4*>((unsigned short*)Cout +
            ((size_t)(mb >> 11) * Dc + n) * Sc + (mb & (Sc - 1))) = ov;
      } else {
#pragma unroll
        for (int jj = 0; jj < 4; ++jj) {
          int m = m0 + wr * 64 + i * 16 + lhi * 4 + jj;
          float v = (acc[i][j][jj] + bv) * scale;
          if (MODE == 1)
            ((unsigned short*)Cout)[(size_t)m * N + n] = f2bf(v);
          else
            ((float*)Cout)[(size_t)m * N + n] = v;
        }
      }
    }
}

// ---------------- Flash attention ----------------
// Q prescaled by log2(e)/sqrt(DK) (softmax in exp2 domain).
// Q/K/X: [B*S][D] bf16; head h = columns [h*64, h*64+64).
// Vt: [B*D][S] bf16 (pre-transposed by the V-projection GEMM).
// Block = (b, h, 128 q-rows); 8 waves x 16 q-rows each.
// Double-buffered K/V^T LDS tiles; prefetch issued BEFORE compute; one
// vmcnt(0)+s_barrier per tile. LDS = 32 KB -> 4 blocks/CU (wave-capped).
// Swapped QK^T (x32): sacc[ct][jj] = S[kv=ct*16+lhi*4+jj][q-row l15].
// PV via 16x16x16 MFMA: A-frag k = lhi*4+i matches sacc's kv granularity,
// so P = exp2(sacc - m) feeds PV DIRECTLY from registers -- no P LDS
// round-trip, no shuffles. Row sums via ones-MFMA into the same layout
// as xacc (no shuffles for rescale or final 1/l).
// Defer-max (THR=8): per-lane check; cross-lane reduce only on rescale tiles.
__global__ void __launch_bounds__(512, 8) attn_kernel(
    const unsigned short* __restrict__ Q, const unsigned short* __restrict__ Kk,
    const unsigned short* __restrict__ Vt, unsigned short* __restrict__ X) {
  __shared__ unsigned short lK[2][64 * 64];   // [kv][dk], XOR-swizzled (both-sides)
  __shared__ unsigned short lVT[2][64 * 64];  // [dk][kv], XOR-swizzled
  const int t = threadIdx.x;
  const int wv = t >> 6, ln = t & 63;
  const int l15 = ln & 15, lhi = ln >> 4;
  const int q0 = blockIdx.x * 128;
  const int h = blockIdx.y, b = blockIdx.z;
  const size_t base = (size_t)b * Sc * Dc;
  const int hoff = h * DKc;

  bf16x8 qf[2];
  {
    const unsigned short* qp = Q + base + (size_t)(q0 + wv * 16 + l15) * Dc + hoff + lhi * 8;
    qf[0] = *reinterpret_cast<const bf16x8*>(qp);
    qf[1] = *reinterpret_cast<const bf16x8*>(qp + 32);
  }

  // staging: 512 threads x 16B = one full 64x64 bf16 tile per buffer.
  // LDS dest LINEAR (global_load_lds constraint); swizzle applied on SOURCE col.
  const int e0 = t * 8;
  const int r0 = e0 >> 6, c0 = (e0 & 63) ^ ((r0 & 7) << 3);
  const unsigned short* kS0 = Kk + base + (size_t)r0 * Dc + hoff + c0;
  const unsigned short* vS0 = Vt + ((size_t)b * Dc + hoff + r0) * Sc + c0;

  float mrow = -1e30f;            // running max for q-row l15 (x4 replicated)
  f32x4 xacc[4] = {};             // out rows lhi*4+jj, cols dt*16+l15
  f32x4 lsum = {};                // row sums for rows lhi*4+jj (ones-MFMA)
  const int swzK = (l15 & 7) << 4;

  bf16x4 ones4;
#pragma unroll
  for (int i = 0; i < 4; ++i) ones4[i] = (bf16_t)1.0f;

#define STAGE(bi, kv0_)                                                    \
  do {                                                                     \
    gload_lds16(kS0 + (size_t)(kv0_)*Dc, (char*)lK[bi] + e0 * 2);          \
    gload_lds16(vS0 + (kv0_), (char*)lVT[bi] + e0 * 2);                    \
  } while (0)

  STAGE(0, 0);
  asm volatile("s_waitcnt vmcnt(0)" ::: "memory");
  __builtin_amdgcn_s_barrier();
  __builtin_amdgcn_sched_barrier(0);

  for (int tt = 0; tt < Sc / 64; ++tt) {
    const int cur = tt & 1;
    if (tt + 1 < Sc / 64) STAGE(cur ^ 1, (tt + 1) * 64); // prefetch next tile

    const unsigned short* K_ = lK[cur];
    const unsigned short* VT_ = lVT[cur];

    // swapped QK^T: sacc[ct][jj] = S[kv0 + ct*16 + lhi*4 + jj][q-row l15]
    f32x4 sacc[4];
#pragma unroll
    for (int ct = 0; ct < 4; ++ct) {
      f32x4 z = {};
#pragma unroll
      for (int kk = 0; kk < 2; ++kk) {
        bf16x8 kf = *reinterpret_cast<const bf16x8*>(
            (const char*)K_ + (((ct * 16 + l15) * 128 + kk * 64 + lhi * 16) ^ swzK));
        z = __builtin_amdgcn_mfma_f32_16x16x32_bf16(kf, qf[kk], z, 0, 0, 0);
      }
      sacc[ct] = z;
    }

    // per-lane max over this lane's 16 scores (no cross-lane yet)
    float mt = fmaxf(fmaxf(sacc[0][0], sacc[0][1]), fmaxf(sacc[0][2], sacc[0][3]));
#pragma unroll
    for (int ct = 1; ct < 4; ++ct)
      mt = fmaxf(mt,
          fmaxf(fmaxf(sacc[ct][0], sacc[ct][1]), fmaxf(sacc[ct][2], sacc[ct][3])));

    // defer-max: rescale only when some lane's max grew past threshold.
    // Stale m keeps P <= 2^8 = 256 — fine in f32 accum / bf16 P.
    if (__any(mt > mrow + 8.0f)) {
      float mtr = fmaxf(mt, __shfl_xor(mt, 16));
      mtr = fmaxf(mtr, __shfl_xor(mtr, 32)); // row max (lanes sharing l15)
      float mnew = fmaxf(mrow, mtr);
      float corr = fexp2(mrow - mnew);
      mrow = mnew;
#pragma unroll
      for (int jj = 0; jj < 4; ++jj) {
        float cO = __shfl(corr, lhi * 4 + jj); // corr of q-row lhi*4+jj
        lsum[jj] *= cO;
#pragma unroll
        for (int dt = 0; dt < 4; ++dt) xacc[dt][jj] *= cO;
      }
    }

    // P fragments in-register: pa[ct] IS the x16 A-fragment for kv-chunk ct
    // (A-frag element k = lhi*4+i  ==  sacc's kv = ct*16 + lhi*4 + jj).
    bf16x4 pa[4];
#pragma unroll
    for (int ct = 0; ct < 4; ++ct)
#pragma unroll
      for (int jj = 0; jj < 4; ++jj)
        pa[ct][jj] = (bf16_t)fexp2(sacc[ct][jj] - mrow);

    // PV + row-sum, all 16x16x16: xacc[dt] += P_ct @ V[ct-chunk][dt-cols]
#pragma unroll
    for (int ct = 0; ct < 4; ++ct) {
      lsum = mfma16(pa[ct], ones4, lsum);
#pragma unroll
      for (int dt = 0; dt < 4; ++dt) {
        // B-frag: col = d (l15), k = kv = ct*16 + lhi*4 + i  -> V^T row
        // (dt*16+l15), 4 consecutive kv at byte ct*32 + lhi*8 (swizzled).
        bf16x4 vb = *reinterpret_cast<const bf16x4*>(
            (const char*)VT_ + ((((dt * 16 + l15) * 128) + ct * 32 + lhi * 8) ^ swzK));
        xacc[dt] = mfma16(pa[ct], vb, xacc[dt]);
      }
    }

    // single drain+barrier per tile
    asm volatile("s_waitcnt vmcnt(0)" ::: "memory");
    __builtin_amdgcn_s_barrier();
    __builtin_amdgcn_sched_barrier(0);
  }
#undef STAGE

  // lsum[jj] is already the row sum for output row lhi*4+jj — no shuffles.
  float iO[4];
#pragma unroll
  for (int jj = 0; jj < 4; ++jj) iO[jj] = 1.0f / lsum[jj];

  unsigned short* xp = X + base + (size_t)(q0 + wv * 16) * Dc + hoff;
#pragma unroll
  for (int dt = 0; dt < 4; ++dt)
#pragma unroll
    for (int jj = 0; jj < 4; ++jj) {
      int r = lhi * 4 + jj;
      xp[(size_t)r * Dc + dt * 16 + l15] = f2bf(xacc[dt][jj] * iO[jj]);
    }
}

// ---------------- launch ----------------
extern "C" void kernel_launch(void* const* d_in, const int* in_sizes, int n_in,
                              void* d_out, int out_size, void* d_ws, size_t ws_size,
                              hipStream_t stream) {
  const float* query = (const float*)d_in[0];
  const float* key   = (const float*)d_in[1];
  const float* value = (const float*)d_in[2];
  const float* Wq = (const float*)d_in[3];
  const float* bq = (const float*)d_in[4];
  const float* Wk = (const float*)d_in[5];
  const float* bk = (const float*)d_in[6];
  const float* Wv = (const float*)d_in[7];
  const float* bv = (const float*)d_in[8];
  const float* Wo = (const float*)d_in[9];
  const float* bo = (const float*)d_in[10];

  const size_t NBS = (size_t)Mrows * Dc; // 8388608
  const size_t NW  = (size_t)Dc * Dc;    // 1048576
  unsigned short* bQin = (unsigned short*)d_ws;
  unsigned short* bKin = bQin + NBS;
  unsigned short* bVin = bKin + NBS;
  unsigned short* bWq  = bVin + NBS;
  unsigned short* bWk  = bWq + NW;
  unsigned short* bWv  = bWk + NW;
  unsigned short* bWo  = bWv + NW;
  unsigned short* Qp   = bWo + NW;
  unsigned short* Kp   = Qp + NBS;
  unsigned short* Vtp  = Kp + NBS; // V projection stored TRANSPOSED: [B*D][S]
  unsigned short* Xp   = Vtp + NBS;

  // inputs: 3 contiguous segments (bQin,bKin,bVin); lg = log2(NBS/4) = 21
  cvt_bf16_seg_kernel<<<(int)(3 * NBS / 1024), 256, 0, stream>>>(
      query, key, value, value, bQin, 21);
  // weights: 4 contiguous segments (bWq..bWo); lg = log2(NW/4) = 18
  cvt_bf16_seg_kernel<<<(int)(4 * NW / 1024), 256, 0, stream>>>(
      Wq, Wk, Wv, Wo, bWq, 18);

  dim3 gg(Dc / 128, Mrows / 128); // (8, 64)
  // Q prescale folds 1/sqrt(DK) AND log2(e) (attn softmax runs in exp2 domain)
  gemm_bt_kernel<1><<<gg, 256, 0, stream>>>(bQin, bWq, bq, Qp, Mrows, Dc, Dc,
                                            0.125f * 1.44269504088896340736f);
  gemm_bt_kernel<1><<<gg, 256, 0, stream>>>(bKin, bWk, bk, Kp, Mrows, Dc, Dc, 1.0f);
  gemm_bt_kernel<2><<<gg, 256, 0, stream>>>(bVin, bWv, bv, Vtp, Mrows, Dc, Dc, 1.0f);

  attn_kernel<<<dim3(Sc / 128, Hc, Bc), 512, 0, stream>>>(Qp, Kp, Vtp, Xp);

  gemm_bt_kernel<0><<<gg, 256, 0, stream>>>(Xp, bWo, bo, d_out, Mrows, Dc, Dc, 1.0f);
}

// Round 4
// 266.620 us; speedup vs baseline: 1.4163x; 1.4163x over previous
//
#include <hip/hip_runtime.h>
#include <stdint.h>

#define DEV static __device__ __forceinline__

typedef __bf16 bf16_t;
typedef bf16_t bf16x8 __attribute__((ext_vector_type(8)));
typedef bf16_t bf16x4 __attribute__((ext_vector_type(4)));
typedef float f32x4 __attribute__((ext_vector_type(4)));

static constexpr int Bc = 4, Sc = 2048, Dc = 1024, Hc = 16, DKc = 64;
static constexpr int Mrows = Bc * Sc; // 8192

DEV unsigned short f2bf(float f) {
  unsigned int u = __float_as_uint(f);
  u += 0x7fffu + ((u >> 16) & 1u);
  return (unsigned short)(u >> 16);
}

DEV float fexp2(float x) {
#if __has_builtin(__builtin_amdgcn_exp2f)
  return __builtin_amdgcn_exp2f(x); // single v_exp_f32
#else
  return exp2f(x);
#endif
}

// 16x16x16 bf16 MFMA (K=16): A-frag k-granularity = lhi*4 -- matches the
// swapped-QK^T D-layout exactly, so P feeds PV straight from registers.
#if __has_builtin(__builtin_amdgcn_mfma_f32_16x16x16_bf16)
DEV f32x4 mfma16(bf16x4 a, bf16x4 b, f32x4 c) {
  return __builtin_amdgcn_mfma_f32_16x16x16_bf16(a, b, c, 0, 0, 0);
}
#elif __has_builtin(__builtin_amdgcn_mfma_f32_16x16x16bf16_1k)
typedef short s16x4 __attribute__((ext_vector_type(4)));
DEV f32x4 mfma16(bf16x4 a, bf16x4 b, f32x4 c) {
  union U { bf16x4 h; s16x4 s; };
  U ua, ub; ua.h = a; ub.h = b;
  return __builtin_amdgcn_mfma_f32_16x16x16bf16_1k(ua.s, ub.s, c, 0, 0, 0);
}
#else
DEV f32x4 mfma16(bf16x4 a, bf16x4 b, f32x4 c) {
  asm("v_mfma_f32_16x16x16_bf16 %0, %1, %2, %0" : "+v"(c) : "v"(a), "v"(b));
  return c;
}
#endif

DEV void gload_lds16(const void* g, void* l) {
  __builtin_amdgcn_global_load_lds(
      (const __attribute__((address_space(1))) void*)g,
      (__attribute__((address_space(3))) void*)l, 16, 0, 0);
}

// ---------------- fp32 -> bf16 conversion (segmented: up to 4 tensors) ------
__global__ void __launch_bounds__(256) cvt_bf16_seg_kernel(
    const float* __restrict__ s0, const float* __restrict__ s1,
    const float* __restrict__ s2, const float* __restrict__ s3,
    unsigned short* __restrict__ out, int lg) {
  int i = blockIdx.x * blockDim.x + threadIdx.x;
  int seg = i >> lg, j = i & ((1 << lg) - 1);
  const float* src = seg == 0 ? s0 : seg == 1 ? s1 : seg == 2 ? s2 : s3;
  float4 v = reinterpret_cast<const float4*>(src)[j];
  ushort4 o;
  o.x = f2bf(v.x); o.y = f2bf(v.y); o.z = f2bf(v.z); o.w = f2bf(v.w);
  reinterpret_cast<ushort4*>(out)[i] = o;
}

// ---------------- GEMM: C[m][n] = (sum_k A[m][k]*W[n][k] + bias[n]) * scale ----
// A: [M][K] bf16 row-major, W: [N][K] bf16 row-major (i.e. X @ W^T)
// 128x128 tile, BK=32, 256 threads (4 waves, 2x2), 4x4 16x16x32 MFMA per wave.
// MODE: 0 = f32 linear out, 1 = bf16 linear out,
//       2 = bf16 TRANSPOSED out with kv-FIELD-SWAP: the s-position within
//           each 64-block is permuted p = ((s>>4)&3)*4 + ((s>>2)&3)*16 + (s&3)
//           (swap bits [5:4]<->[3:2]). This pre-composes the attention PV
//           fragment layout into Vt's global layout so attn's PV can use
//           paired ds_read_b128 with zero cross-lane movement.
template <int MODE>
__global__ void __launch_bounds__(256) gemm_bt_kernel(
    const unsigned short* __restrict__ A, const unsigned short* __restrict__ W,
    const float* __restrict__ bias, void* __restrict__ Cout,
    int M, int N, int K, float scale) {
  __shared__ unsigned short lA[128 * 32];
  __shared__ unsigned short lB[128 * 32];
  const int t = threadIdx.x;
  const int wv = t >> 6, ln = t & 63;
  const int l15 = ln & 15, lhi = ln >> 4;
  const int m0 = blockIdx.y * 128, n0 = blockIdx.x * 128;
  const int wr = wv >> 1, wc = wv & 1;

  f32x4 acc[4][4] = {};

  for (int k0 = 0; k0 < K; k0 += 32) {
    __syncthreads();
#pragma unroll
    for (int r = 0; r < 2; ++r) {
      int e = r * 2048 + t * 8;
      int row = e >> 5, col = e & 31;
      gload_lds16(A + (size_t)(m0 + row) * K + k0 + col, (char*)lA + e * 2);
      gload_lds16(W + (size_t)(n0 + row) * K + k0 + col, (char*)lB + e * 2);
    }
    __syncthreads();
    bf16x8 af[4], bfr[4];
#pragma unroll
    for (int i = 0; i < 4; ++i)
      af[i] = *reinterpret_cast<const bf16x8*>(&lA[(wr * 64 + i * 16 + l15) * 32 + lhi * 8]);
#pragma unroll
    for (int j = 0; j < 4; ++j)
      bfr[j] = *reinterpret_cast<const bf16x8*>(&lB[(wc * 64 + j * 16 + l15) * 32 + lhi * 8]);
#pragma unroll
    for (int i = 0; i < 4; ++i)
#pragma unroll
      for (int j = 0; j < 4; ++j)
        acc[i][j] = __builtin_amdgcn_mfma_f32_16x16x32_bf16(af[i], bfr[j], acc[i][j], 0, 0, 0);
  }

#pragma unroll
  for (int i = 0; i < 4; ++i)
#pragma unroll
    for (int j = 0; j < 4; ++j) {
      int n = n0 + wc * 64 + j * 16 + l15;
      float bv = bias[n];
      if (MODE == 2) {
        int mb = m0 + wr * 64 + i * 16 + lhi * 4; // 4 consecutive m = consecutive s
        int sl = mb & (Sc - 1);
        // field-swap bits [5:4]<->[3:2] of the 64-block position (low 2 bits
        // untouched -> the ushort4 store stays contiguous)
        int pl = (sl & ~60) | ((sl & 48) >> 2) | ((sl & 12) << 2);
        ushort4 ov;
        ov.x = f2bf((acc[i][j][0] + bv) * scale);
        ov.y = f2bf((acc[i][j][1] + bv) * scale);
        ov.z = f2bf((acc[i][j][2] + bv) * scale);
        ov.w = f2bf((acc[i][j][3] + bv) * scale);
        *reinterpret_cast<ushort4*>((unsigned short*)Cout +
            ((size_t)(mb >> 11) * Dc + n) * Sc + pl) = ov;
      } else {
#pragma unroll
        for (int jj = 0; jj < 4; ++jj) {
          int m = m0 + wr * 64 + i * 16 + lhi * 4 + jj;
          float v = (acc[i][j][jj] + bv) * scale;
          if (MODE == 1)
            ((unsigned short*)Cout)[(size_t)m * N + n] = f2bf(v);
          else
            ((float*)Cout)[(size_t)m * N + n] = v;
        }
      }
    }
}

// ---------------- Flash attention ----------------
// Q prescaled by log2(e)/sqrt(DK) (softmax in exp2 domain).
// Q/K/X: [B*S][D] bf16; head h = columns [h*64, h*64+64).
// Vt: [B*D][S] bf16, kv-field-swapped within each 64-block (see MODE 2).
// Block = (b, h, 128 q-rows); 8 waves x 16 q-rows each.
// __launch_bounds__(512, 4): 128-VGPR cap. (512,8) forced a 64-VGPR cap and
// spilled the accumulators to scratch -> 4.8x FETCH_SIZE, 2x slower (R3).
// Double-buffered K/V^T LDS tiles; prefetch BEFORE compute; one
// vmcnt(0)+s_barrier per tile. LDS = 32 KB.
// Swapped QK^T (x32): sacc[ct][jj] = S[kv=ct*16+lhi*4+jj][q-row l15].
// PV via 16x16x16 MFMA: A-frag k = lhi*4+i == sacc's kv granularity, so
// P = exp2(sacc - m) feeds PV DIRECTLY from registers. The field-swapped Vt
// layout makes each ct-PAIR's B-fragments one contiguous swizzled 16B run ->
// 8 ds_read_b128/tile, bank-uniform (32 B/bank/wave, conflict-free).
// Row sums via ones-MFMA (same layout as xacc -> no shuffles anywhere).
// Defer-max (THR=8): per-lane check; cross-lane reduce only on rescale tiles.
__global__ void __launch_bounds__(512, 4) attn_kernel(
    const unsigned short* __restrict__ Q, const unsigned short* __restrict__ Kk,
    const unsigned short* __restrict__ Vt, unsigned short* __restrict__ X) {
  __shared__ unsigned short lK[2][64 * 64];   // [kv][dk], XOR-swizzled (both-sides)
  __shared__ unsigned short lVT[2][64 * 64];  // [dk][swapped-kv], XOR-swizzled
  const int t = threadIdx.x;
  const int wv = t >> 6, ln = t & 63;
  const int l15 = ln & 15, lhi = ln >> 4;
  const int q0 = blockIdx.x * 128;
  const int h = blockIdx.y, b = blockIdx.z;
  const size_t base = (size_t)b * Sc * Dc;
  const int hoff = h * DKc;

  bf16x8 qf[2];
  {
    const unsigned short* qp = Q + base + (size_t)(q0 + wv * 16 + l15) * Dc + hoff + lhi * 8;
    qf[0] = *reinterpret_cast<const bf16x8*>(qp);
    qf[1] = *reinterpret_cast<const bf16x8*>(qp + 32);
  }

  // staging: 512 threads x 16B = one full 64x64 bf16 tile per buffer.
  // LDS dest LINEAR (global_load_lds constraint); swizzle applied on SOURCE
  // col. (For Vt the fragment-perm is already in the global layout, so the
  // staging address math is identical for K and Vt.)
  const int e0 = t * 8;
  const int r0 = e0 >> 6, c0 = (e0 & 63) ^ ((r0 & 7) << 3);
  const unsigned short* kS0 = Kk + base + (size_t)r0 * Dc + hoff + c0;
  const unsigned short* vS0 = Vt + ((size_t)b * Dc + hoff + r0) * Sc + c0;

  float mrow = -1e30f;            // running max for q-row l15 (x4 replicated)
  f32x4 xacc[4] = {};             // out rows lhi*4+jj, cols dt*16+l15
  f32x4 lsum = {};                // row sums for rows lhi*4+jj (ones-MFMA)
  const int swzK = (l15 & 7) << 4;

  bf16x4 ones4;
#pragma unroll
  for (int i = 0; i < 4; ++i) ones4[i] = (bf16_t)1.0f;

#define STAGE(bi, kv0_)                                                    \
  do {                                                                     \
    gload_lds16(kS0 + (size_t)(kv0_)*Dc, (char*)lK[bi] + e0 * 2);          \
    gload_lds16(vS0 + (kv0_), (char*)lVT[bi] + e0 * 2);                    \
  } while (0)

  STAGE(0, 0);
  asm volatile("s_waitcnt vmcnt(0)" ::: "memory");
  __builtin_amdgcn_s_barrier();
  __builtin_amdgcn_sched_barrier(0);

  for (int tt = 0; tt < Sc / 64; ++tt) {
    const int cur = tt & 1;
    if (tt + 1 < Sc / 64) STAGE(cur ^ 1, (tt + 1) * 64); // prefetch next tile

    const unsigned short* K_ = lK[cur];
    const unsigned short* VT_ = lVT[cur];

    // swapped QK^T: sacc[ct][jj] = S[kv0 + ct*16 + lhi*4 + jj][q-row l15]
    f32x4 sacc[4];
#pragma unroll
    for (int ct = 0; ct < 4; ++ct) {
      f32x4 z = {};
#pragma unroll
      for (int kk = 0; kk < 2; ++kk) {
        bf16x8 kf = *reinterpret_cast<const bf16x8*>(
            (const char*)K_ + (((ct * 16 + l15) * 128 + kk * 64 + lhi * 16) ^ swzK));
        z = __builtin_amdgcn_mfma_f32_16x16x32_bf16(kf, qf[kk], z, 0, 0, 0);
      }
      sacc[ct] = z;
    }

    // per-lane max over this lane's 16 scores (no cross-lane yet)
    float mt = fmaxf(fmaxf(sacc[0][0], sacc[0][1]), fmaxf(sacc[0][2], sacc[0][3]));
#pragma unroll
    for (int ct = 1; ct < 4; ++ct)
      mt = fmaxf(mt,
          fmaxf(fmaxf(sacc[ct][0], sacc[ct][1]), fmaxf(sacc[ct][2], sacc[ct][3])));

    // defer-max: rescale only when some lane's max grew past threshold.
    // Stale m keeps P <= 2^8 = 256 — fine in f32 accum / bf16 P.
    if (__any(mt > mrow + 8.0f)) {
      float mtr = fmaxf(mt, __shfl_xor(mt, 16));
      mtr = fmaxf(mtr, __shfl_xor(mtr, 32)); // row max (lanes sharing l15)
      float mnew = fmaxf(mrow, mtr);
      float corr = fexp2(mrow - mnew);
      mrow = mnew;
#pragma unroll
      for (int jj = 0; jj < 4; ++jj) {
        float cO = __shfl(corr, lhi * 4 + jj); // corr of q-row lhi*4+jj
        lsum[jj] *= cO;
#pragma unroll
        for (int dt = 0; dt < 4; ++dt) xacc[dt][jj] *= cO;
      }
    }

    // P fragments in-register: pa[ct] IS the x16 A-fragment for kv-chunk ct
    bf16x4 pa[4];
#pragma unroll
    for (int ct = 0; ct < 4; ++ct)
#pragma unroll
      for (int jj = 0; jj < 4; ++jj)
        pa[ct][jj] = (bf16_t)fexp2(sacc[ct][jj] - mrow);

    // row-sum via ones-MFMA
#pragma unroll
    for (int ct = 0; ct < 4; ++ct) lsum = mfma16(pa[ct], ones4, lsum);

    // PV: one b128 per (dt, ct-pair) holds BOTH x16 B-fragments
    // (field-swapped Vt layout: row byte = lhi*32 + sel*16, elems 0-3 ->
    //  ct=2*sel, elems 4-7 -> ct=2*sel+1; k-within-chunk = lhi*4+i).
#pragma unroll
    for (int dt = 0; dt < 4; ++dt) {
#pragma unroll
      for (int sel = 0; sel < 2; ++sel) {
        bf16x8 vb2 = *reinterpret_cast<const bf16x8*>(
            (const char*)VT_ + (((dt * 16 + l15) * 128 + lhi * 32 + sel * 16) ^ swzK));
        bf16x4 vlo = __builtin_shufflevector(vb2, vb2, 0, 1, 2, 3);
        bf16x4 vhi = __builtin_shufflevector(vb2, vb2, 4, 5, 6, 7);
        xacc[dt] = mfma16(pa[2 * sel + 0], vlo, xacc[dt]);
        xacc[dt] = mfma16(pa[2 * sel + 1], vhi, xacc[dt]);
      }
    }

    // single drain+barrier per tile
    asm volatile("s_waitcnt vmcnt(0)" ::: "memory");
    __builtin_amdgcn_s_barrier();
    __builtin_amdgcn_sched_barrier(0);
  }
#undef STAGE

  // lsum[jj] is already the row sum for output row lhi*4+jj — no shuffles.
  float iO[4];
#pragma unroll
  for (int jj = 0; jj < 4; ++jj) iO[jj] = 1.0f / lsum[jj];

  unsigned short* xp = X + base + (size_t)(q0 + wv * 16) * Dc + hoff;
#pragma unroll
  for (int dt = 0; dt < 4; ++dt)
#pragma unroll
    for (int jj = 0; jj < 4; ++jj) {
      int r = lhi * 4 + jj;
      xp[(size_t)r * Dc + dt * 16 + l15] = f2bf(xacc[dt][jj] * iO[jj]);
    }
}

// ---------------- launch ----------------
extern "C" void kernel_launch(void* const* d_in, const int* in_sizes, int n_in,
                              void* d_out, int out_size, void* d_ws, size_t ws_size,
                              hipStream_t stream) {
  const float* query = (const float*)d_in[0];
  const float* key   = (const float*)d_in[1];
  const float* value = (const float*)d_in[2];
  const float* Wq = (const float*)d_in[3];
  const float* bq = (const float*)d_in[4];
  const float* Wk = (const float*)d_in[5];
  const float* bk = (const float*)d_in[6];
  const float* Wv = (const float*)d_in[7];
  const float* bv = (const float*)d_in[8];
  const float* Wo = (const float*)d_in[9];
  const float* bo = (const float*)d_in[10];

  const size_t NBS = (size_t)Mrows * Dc; // 8388608
  const size_t NW  = (size_t)Dc * Dc;    // 1048576
  unsigned short* bQin = (unsigned short*)d_ws;
  unsigned short* bKin = bQin + NBS;
  unsigned short* bVin = bKin + NBS;
  unsigned short* bWq  = bVin + NBS;
  unsigned short* bWk  = bWq + NW;
  unsigned short* bWv  = bWk + NW;
  unsigned short* bWo  = bWv + NW;
  unsigned short* Qp   = bWo + NW;
  unsigned short* Kp   = Qp + NBS;
  unsigned short* Vtp  = Kp + NBS; // V projection, TRANSPOSED + field-swapped
  unsigned short* Xp   = Vtp + NBS;

  // inputs: 3 contiguous segments (bQin,bKin,bVin); lg = log2(NBS/4) = 21
  cvt_bf16_seg_kernel<<<(int)(3 * NBS / 1024), 256, 0, stream>>>(
      query, key, value, value, bQin, 21);
  // weights: 4 contiguous segments (bWq..bWo); lg = log2(NW/4) = 18
  cvt_bf16_seg_kernel<<<(int)(4 * NW / 1024), 256, 0, stream>>>(
      Wq, Wk, Wv, Wo, bWq, 18);

  dim3 gg(Dc / 128, Mrows / 128); // (8, 64)
  // Q prescale folds 1/sqrt(DK) AND log2(e) (attn softmax runs in exp2 domain)
  gemm_bt_kernel<1><<<gg, 256, 0, stream>>>(bQin, bWq, bq, Qp, Mrows, Dc, Dc,
                                            0.125f * 1.44269504088896340736f);
  gemm_bt_kernel<1><<<gg, 256, 0, stream>>>(bKin, bWk, bk, Kp, Mrows, Dc, Dc, 1.0f);
  gemm_bt_kernel<2><<<gg, 256, 0, stream>>>(bVin, bWv, bv, Vtp, Mrows, Dc, Dc, 1.0f);

  attn_kernel<<<dim3(Sc / 128, Hc, Bc), 512, 0, stream>>>(Qp, Kp, Vtp, Xp);

  gemm_bt_kernel<0><<<gg, 256, 0, stream>>>(Xp, bWo, bo, d_out, Mrows, Dc, Dc, 1.0f);
}

// Round 5
// 237.231 us; speedup vs baseline: 1.5918x; 1.1239x over previous
//
#include <hip/hip_runtime.h>
#include <stdint.h>

#define DEV static __device__ __forceinline__

typedef __bf16 bf16_t;
typedef bf16_t bf16x8 __attribute__((ext_vector_type(8)));
typedef bf16_t bf16x4 __attribute__((ext_vector_type(4)));
typedef float f32x4 __attribute__((ext_vector_type(4)));

static constexpr int Bc = 4, Sc = 2048, Dc = 1024, Hc = 16, DKc = 64;
static constexpr int Mrows = Bc * Sc; // 8192

DEV unsigned short f2bf(float f) {
  unsigned int u = __float_as_uint(f);
  u += 0x7fffu + ((u >> 16) & 1u);
  return (unsigned short)(u >> 16);
}

DEV float fexp2(float x) {
#if __has_builtin(__builtin_amdgcn_exp2f)
  return __builtin_amdgcn_exp2f(x); // single v_exp_f32
#else
  return exp2f(x);
#endif
}

// 16x16x16 bf16 MFMA (K=16): A-frag k-granularity = lhi*4 -- matches the
// swapped-QK^T D-layout exactly, so P feeds PV straight from registers.
#if __has_builtin(__builtin_amdgcn_mfma_f32_16x16x16_bf16)
DEV f32x4 mfma16(bf16x4 a, bf16x4 b, f32x4 c) {
  return __builtin_amdgcn_mfma_f32_16x16x16_bf16(a, b, c, 0, 0, 0);
}
#elif __has_builtin(__builtin_amdgcn_mfma_f32_16x16x16bf16_1k)
typedef short s16x4 __attribute__((ext_vector_type(4)));
DEV f32x4 mfma16(bf16x4 a, bf16x4 b, f32x4 c) {
  union U { bf16x4 h; s16x4 s; };
  U ua, ub; ua.h = a; ub.h = b;
  return __builtin_amdgcn_mfma_f32_16x16x16bf16_1k(ua.s, ub.s, c, 0, 0, 0);
}
#else
DEV f32x4 mfma16(bf16x4 a, bf16x4 b, f32x4 c) {
  asm("v_mfma_f32_16x16x16_bf16 %0, %1, %2, %0" : "+v"(c) : "v"(a), "v"(b));
  return c;
}
#endif

DEV void gload_lds16(const void* g, void* l) {
  __builtin_amdgcn_global_load_lds(
      (const __attribute__((address_space(1))) void*)g,
      (__attribute__((address_space(3))) void*)l, 16, 0, 0);
}

// ---------------- fp32 -> bf16 conversion (segmented: up to 4 tensors) ------
__global__ void __launch_bounds__(256) cvt_bf16_seg_kernel(
    const float* __restrict__ s0, const float* __restrict__ s1,
    const float* __restrict__ s2, const float* __restrict__ s3,
    unsigned short* __restrict__ out, int lg) {
  int i = blockIdx.x * blockDim.x + threadIdx.x;
  int seg = i >> lg, j = i & ((1 << lg) - 1);
  const float* src = seg == 0 ? s0 : seg == 1 ? s1 : seg == 2 ? s2 : s3;
  float4 v = reinterpret_cast<const float4*>(src)[j];
  ushort4 o;
  o.x = f2bf(v.x); o.y = f2bf(v.y); o.z = f2bf(v.z); o.w = f2bf(v.w);
  reinterpret_cast<ushort4*>(out)[i] = o;
}

// ---------------- GEMM: C[m][n] = (sum_k A[m][k]*W[n][k] + bias[n]) * scale ----
// A: [M][K] bf16 row-major, W: [N][K] bf16 row-major (i.e. X @ W^T)
// 128x128 tile, BK=64, 256 threads (4 waves, 2x2), 4x4 16x16x32 MFMA per wave
// per k-half. BK=64 halves the per-K-step barrier-drain stalls vs BK=32.
// LDS row stride at BK=64 is 128 B = exact bank period, so the tile is
// XOR-swizzled: global SOURCE col ^ ((row&7)<<3) with LINEAR LDS dest
// (global_load_lds constraint), fragment reads XOR (l15&7)<<4 -- the same
// both-sides pattern as the attention staging.
// XCD swizzle: hw block id -> (hw%8)*chunk + hw/8 so each XCD gets 8
// consecutive m-panels x all n-blocks; A-panel (2MB) + B (2MB) fit its L2.
// MODE: 0 = f32 linear out, 1 = bf16 linear out,
//       2 = bf16 TRANSPOSED out with kv-FIELD-SWAP (bits [5:4]<->[3:2] of
//           s&63) pre-composing attn's PV fragment layout into Vt.
template <int MODE>
__global__ void __launch_bounds__(256) gemm_bt_kernel(
    const unsigned short* __restrict__ A, const unsigned short* __restrict__ W,
    const float* __restrict__ bias, void* __restrict__ Cout,
    int M, int N, int K, float scale) {
  __shared__ unsigned short lA[128 * 64];
  __shared__ unsigned short lB[128 * 64];
  const int t = threadIdx.x;
  const int wv = t >> 6, ln = t & 63;
  const int l15 = ln & 15, lhi = ln >> 4;

  // XCD-chunked remap (bijective; grid size is a multiple of 8 here: 512)
  const int nwg = gridDim.x * gridDim.y;
  const int hw = blockIdx.y * gridDim.x + blockIdx.x;
  const int chunk = nwg >> 3;
  const int swzid = (hw & 7) * chunk + (hw >> 3);
  const int m0 = (swzid / gridDim.x) * 128, n0 = (swzid % gridDim.x) * 128;
  const int wr = wv >> 1, wc = wv & 1;
  const int swzR = (l15 & 7) << 4; // fragment-read XOR (row&7 == l15&7)

  f32x4 acc[4][4] = {};

  for (int k0 = 0; k0 < K; k0 += 64) {
    __syncthreads();
#pragma unroll
    for (int r = 0; r < 4; ++r) {
      int e = r * 2048 + t * 8;
      int row = e >> 6, col = (e & 63) ^ ((row & 7) << 3); // pre-swizzled src
      gload_lds16(A + (size_t)(m0 + row) * K + k0 + col, (char*)lA + e * 2);
      gload_lds16(W + (size_t)(n0 + row) * K + k0 + col, (char*)lB + e * 2);
    }
    __syncthreads();
#pragma unroll
    for (int kk = 0; kk < 2; ++kk) {
      bf16x8 af[4], bfr[4];
#pragma unroll
      for (int i = 0; i < 4; ++i)
        af[i] = *reinterpret_cast<const bf16x8*>(
            (char*)lA + (((wr * 64 + i * 16 + l15) * 128 + kk * 64 + lhi * 16) ^ swzR));
#pragma unroll
      for (int j = 0; j < 4; ++j)
        bfr[j] = *reinterpret_cast<const bf16x8*>(
            (char*)lB + (((wc * 64 + j * 16 + l15) * 128 + kk * 64 + lhi * 16) ^ swzR));
#pragma unroll
      for (int i = 0; i < 4; ++i)
#pragma unroll
        for (int j = 0; j < 4; ++j)
          acc[i][j] = __builtin_amdgcn_mfma_f32_16x16x32_bf16(af[i], bfr[j], acc[i][j], 0, 0, 0);
    }
  }

#pragma unroll
  for (int i = 0; i < 4; ++i)
#pragma unroll
    for (int j = 0; j < 4; ++j) {
      int n = n0 + wc * 64 + j * 16 + l15;
      float bv = bias[n];
      if (MODE == 2) {
        int mb = m0 + wr * 64 + i * 16 + lhi * 4; // 4 consecutive m = consecutive s
        int sl = mb & (Sc - 1);
        // field-swap bits [5:4]<->[3:2] of the 64-block position (low 2 bits
        // untouched -> the ushort4 store stays contiguous)
        int pl = (sl & ~60) | ((sl & 48) >> 2) | ((sl & 12) << 2);
        ushort4 ov;
        ov.x = f2bf((acc[i][j][0] + bv) * scale);
        ov.y = f2bf((acc[i][j][1] + bv) * scale);
        ov.z = f2bf((acc[i][j][2] + bv) * scale);
        ov.w = f2bf((acc[i][j][3] + bv) * scale);
        *reinterpret_cast<ushort4*>((unsigned short*)Cout +
            ((size_t)(mb >> 11) * Dc + n) * Sc + pl) = ov;
      } else {
#pragma unroll
        for (int jj = 0; jj < 4; ++jj) {
          int m = m0 + wr * 64 + i * 16 + lhi * 4 + jj;
          float v = (acc[i][j][jj] + bv) * scale;
          if (MODE == 1)
            ((unsigned short*)Cout)[(size_t)m * N + n] = f2bf(v);
          else
            ((float*)Cout)[(size_t)m * N + n] = v;
        }
      }
    }
}

// ---------------- Flash attention ----------------
// Q prescaled by log2(e)/sqrt(DK) (softmax in exp2 domain).
// Q/K/X: [B*S][D] bf16; head h = columns [h*64, h*64+64).
// Vt: [B*D][S] bf16, kv-field-swapped within each 64-block (see MODE 2).
// Block = (b, h, 128 q-rows); 8 waves x 16 q-rows each.
// __launch_bounds__(512, 4): 128-VGPR cap. (512,8) forced a 64-VGPR cap and
// spilled the accumulators to scratch -> 4.8x FETCH_SIZE, 2x slower (R3).
// Double-buffered K/V^T LDS tiles; prefetch BEFORE compute; one
// vmcnt(0)+s_barrier per tile. LDS = 32 KB.
// Swapped QK^T (x32): sacc[ct][jj] = S[kv=ct*16+lhi*4+jj][q-row l15].
// PV via 16x16x16 MFMA: A-frag k = lhi*4+i == sacc's kv granularity, so
// P = exp2(sacc - m) feeds PV DIRECTLY from registers. The field-swapped Vt
// layout makes each ct-PAIR's B-fragments one contiguous swizzled 16B run.
// Row sums via ones-MFMA (same layout as xacc -> no shuffles anywhere).
// Defer-max (THR=8): per-lane check; cross-lane reduce only on rescale tiles.
__global__ void __launch_bounds__(512, 4) attn_kernel(
    const unsigned short* __restrict__ Q, const unsigned short* __restrict__ Kk,
    const unsigned short* __restrict__ Vt, unsigned short* __restrict__ X) {
  __shared__ unsigned short lK[2][64 * 64];   // [kv][dk], XOR-swizzled (both-sides)
  __shared__ unsigned short lVT[2][64 * 64];  // [dk][swapped-kv], XOR-swizzled
  const int t = threadIdx.x;
  const int wv = t >> 6, ln = t & 63;
  const int l15 = ln & 15, lhi = ln >> 4;
  const int q0 = blockIdx.x * 128;
  const int h = blockIdx.y, b = blockIdx.z;
  const size_t base = (size_t)b * Sc * Dc;
  const int hoff = h * DKc;

  bf16x8 qf[2];
  {
    const unsigned short* qp = Q + base + (size_t)(q0 + wv * 16 + l15) * Dc + hoff + lhi * 8;
    qf[0] = *reinterpret_cast<const bf16x8*>(qp);
    qf[1] = *reinterpret_cast<const bf16x8*>(qp + 32);
  }

  // staging: 512 threads x 16B = one full 64x64 bf16 tile per buffer.
  // LDS dest LINEAR (global_load_lds constraint); swizzle applied on SOURCE
  // col. (For Vt the fragment-perm is already in the global layout, so the
  // staging address math is identical for K and Vt.)
  const int e0 = t * 8;
  const int r0 = e0 >> 6, c0 = (e0 & 63) ^ ((r0 & 7) << 3);
  const unsigned short* kS0 = Kk + base + (size_t)r0 * Dc + hoff + c0;
  const unsigned short* vS0 = Vt + ((size_t)b * Dc + hoff + r0) * Sc + c0;

  float mrow = -1e30f;            // running max for q-row l15 (x4 replicated)
  f32x4 xacc[4] = {};             // out rows lhi*4+jj, cols dt*16+l15
  f32x4 lsum = {};                // row sums for rows lhi*4+jj (ones-MFMA)
  const int swzK = (l15 & 7) << 4;

  bf16x4 ones4;
#pragma unroll
  for (int i = 0; i < 4; ++i) ones4[i] = (bf16_t)1.0f;

#define STAGE(bi, kv0_)                                                    \
  do {                                                                     \
    gload_lds16(kS0 + (size_t)(kv0_)*Dc, (char*)lK[bi] + e0 * 2);          \
    gload_lds16(vS0 + (kv0_), (char*)lVT[bi] + e0 * 2);                    \
  } while (0)

  STAGE(0, 0);
  asm volatile("s_waitcnt vmcnt(0)" ::: "memory");
  __builtin_amdgcn_s_barrier();
  __builtin_amdgcn_sched_barrier(0);

  for (int tt = 0; tt < Sc / 64; ++tt) {
    const int cur = tt & 1;
    if (tt + 1 < Sc / 64) STAGE(cur ^ 1, (tt + 1) * 64); // prefetch next tile

    const unsigned short* K_ = lK[cur];
    const unsigned short* VT_ = lVT[cur];

    // swapped QK^T: sacc[ct][jj] = S[kv0 + ct*16 + lhi*4 + jj][q-row l15]
    f32x4 sacc[4];
#pragma unroll
    for (int ct = 0; ct < 4; ++ct) {
      f32x4 z = {};
#pragma unroll
      for (int kk = 0; kk < 2; ++kk) {
        bf16x8 kf = *reinterpret_cast<const bf16x8*>(
            (const char*)K_ + (((ct * 16 + l15) * 128 + kk * 64 + lhi * 16) ^ swzK));
        z = __builtin_amdgcn_mfma_f32_16x16x32_bf16(kf, qf[kk], z, 0, 0, 0);
      }
      sacc[ct] = z;
    }

    // per-lane max over this lane's 16 scores (no cross-lane yet)
    float mt = fmaxf(fmaxf(sacc[0][0], sacc[0][1]), fmaxf(sacc[0][2], sacc[0][3]));
#pragma unroll
    for (int ct = 1; ct < 4; ++ct)
      mt = fmaxf(mt,
          fmaxf(fmaxf(sacc[ct][0], sacc[ct][1]), fmaxf(sacc[ct][2], sacc[ct][3])));

    // defer-max: rescale only when some lane's max grew past threshold.
    // Stale m keeps P <= 2^8 = 256 — fine in f32 accum / bf16 P.
    if (__any(mt > mrow + 8.0f)) {
      float mtr = fmaxf(mt, __shfl_xor(mt, 16));
      mtr = fmaxf(mtr, __shfl_xor(mtr, 32)); // row max (lanes sharing l15)
      float mnew = fmaxf(mrow, mtr);
      float corr = fexp2(mrow - mnew);
      mrow = mnew;
#pragma unroll
      for (int jj = 0; jj < 4; ++jj) {
        float cO = __shfl(corr, lhi * 4 + jj); // corr of q-row lhi*4+jj
        lsum[jj] *= cO;
#pragma unroll
        for (int dt = 0; dt < 4; ++dt) xacc[dt][jj] *= cO;
      }
    }

    // P fragments in-register: pa[ct] IS the x16 A-fragment for kv-chunk ct
    bf16x4 pa[4];
#pragma unroll
    for (int ct = 0; ct < 4; ++ct)
#pragma unroll
      for (int jj = 0; jj < 4; ++jj)
        pa[ct][jj] = (bf16_t)fexp2(sacc[ct][jj] - mrow);

    // row-sum via ones-MFMA
#pragma unroll
    for (int ct = 0; ct < 4; ++ct) lsum = mfma16(pa[ct], ones4, lsum);

    // PV: one b128 per (dt, ct-pair) holds BOTH x16 B-fragments
#pragma unroll
    for (int dt = 0; dt < 4; ++dt) {
#pragma unroll
      for (int sel = 0; sel < 2; ++sel) {
        bf16x8 vb2 = *reinterpret_cast<const bf16x8*>(
            (const char*)VT_ + (((dt * 16 + l15) * 128 + lhi * 32 + sel * 16) ^ swzK));
        bf16x4 vlo = __builtin_shufflevector(vb2, vb2, 0, 1, 2, 3);
        bf16x4 vhi = __builtin_shufflevector(vb2, vb2, 4, 5, 6, 7);
        xacc[dt] = mfma16(pa[2 * sel + 0], vlo, xacc[dt]);
        xacc[dt] = mfma16(pa[2 * sel + 1], vhi, xacc[dt]);
      }
    }

    // single drain+barrier per tile
    asm volatile("s_waitcnt vmcnt(0)" ::: "memory");
    __builtin_amdgcn_s_barrier();
    __builtin_amdgcn_sched_barrier(0);
  }
#undef STAGE

  // lsum[jj] is already the row sum for output row lhi*4+jj — no shuffles.
  float iO[4];
#pragma unroll
  for (int jj = 0; jj < 4; ++jj) iO[jj] = 1.0f / lsum[jj];

  unsigned short* xp = X + base + (size_t)(q0 + wv * 16) * Dc + hoff;
#pragma unroll
  for (int dt = 0; dt < 4; ++dt)
#pragma unroll
    for (int jj = 0; jj < 4; ++jj) {
      int r = lhi * 4 + jj;
      xp[(size_t)r * Dc + dt * 16 + l15] = f2bf(xacc[dt][jj] * iO[jj]);
    }
}

// ---------------- launch ----------------
extern "C" void kernel_launch(void* const* d_in, const int* in_sizes, int n_in,
                              void* d_out, int out_size, void* d_ws, size_t ws_size,
                              hipStream_t stream) {
  const float* query = (const float*)d_in[0];
  const float* key   = (const float*)d_in[1];
  const float* value = (const float*)d_in[2];
  const float* Wq = (const float*)d_in[3];
  const float* bq = (const float*)d_in[4];
  const float* Wk = (const float*)d_in[5];
  const float* bk = (const float*)d_in[6];
  const float* Wv = (const float*)d_in[7];
  const float* bv = (const float*)d_in[8];
  const float* Wo = (const float*)d_in[9];
  const float* bo = (const float*)d_in[10];

  const size_t NBS = (size_t)Mrows * Dc; // 8388608
  const size_t NW  = (size_t)Dc * Dc;    // 1048576
  unsigned short* bQin = (unsigned short*)d_ws;
  unsigned short* bKin = bQin + NBS;
  unsigned short* bVin = bKin + NBS;
  unsigned short* bWq  = bVin + NBS;
  unsigned short* bWk  = bWq + NW;
  unsigned short* bWv  = bWk + NW;
  unsigned short* bWo  = bWv + NW;
  unsigned short* Qp   = bWo + NW;
  unsigned short* Kp   = Qp + NBS;
  unsigned short* Vtp  = Kp + NBS; // V projection, TRANSPOSED + field-swapped
  unsigned short* Xp   = Vtp + NBS;

  // inputs: 3 contiguous segments (bQin,bKin,bVin); lg = log2(NBS/4) = 21
  cvt_bf16_seg_kernel<<<(int)(3 * NBS / 1024), 256, 0, stream>>>(
      query, key, value, value, bQin, 21);
  // weights: 4 contiguous segments (bWq..bWo); lg = log2(NW/4) = 18
  cvt_bf16_seg_kernel<<<(int)(4 * NW / 1024), 256, 0, stream>>>(
      Wq, Wk, Wv, Wo, bWq, 18);

  dim3 gg(Dc / 128, Mrows / 128); // (8, 64)
  // Q prescale folds 1/sqrt(DK) AND log2(e) (attn softmax runs in exp2 domain)
  gemm_bt_kernel<1><<<gg, 256, 0, stream>>>(bQin, bWq, bq, Qp, Mrows, Dc, Dc,
                                            0.125f * 1.44269504088896340736f);
  gemm_bt_kernel<1><<<gg, 256, 0, stream>>>(bKin, bWk, bk, Kp, Mrows, Dc, Dc, 1.0f);
  gemm_bt_kernel<2><<<gg, 256, 0, stream>>>(bVin, bWv, bv, Vtp, Mrows, Dc, Dc, 1.0f);

  attn_kernel<<<dim3(Sc / 128, Hc, Bc), 512, 0, stream>>>(Qp, Kp, Vtp, Xp);

  gemm_bt_kernel<0><<<gg, 256, 0, stream>>>(Xp, bWo, bo, d_out, Mrows, Dc, Dc, 1.0f);
}

// Round 6
// 234.935 us; speedup vs baseline: 1.6074x; 1.0098x over previous
//
#include <hip/hip_runtime.h>
#include <stdint.h>

#define DEV static __device__ __forceinline__

typedef __bf16 bf16_t;
typedef bf16_t bf16x8 __attribute__((ext_vector_type(8)));
typedef bf16_t bf16x4 __attribute__((ext_vector_type(4)));
typedef float f32x4 __attribute__((ext_vector_type(4)));

static constexpr int Bc = 4, Sc = 2048, Dc = 1024, Hc = 16, DKc = 64;
static constexpr int Mrows = Bc * Sc; // 8192

DEV unsigned short f2bf(float f) {
  unsigned int u = __float_as_uint(f);
  u += 0x7fffu + ((u >> 16) & 1u);
  return (unsigned short)(u >> 16);
}

DEV float fexp2(float x) {
#if __has_builtin(__builtin_amdgcn_exp2f)
  return __builtin_amdgcn_exp2f(x); // single v_exp_f32
#else
  return exp2f(x);
#endif
}

// 16x16x16 bf16 MFMA (K=16): A-frag k-granularity = lhi*4 -- matches the
// swapped-QK^T D-layout exactly, so P feeds PV straight from registers.
#if __has_builtin(__builtin_amdgcn_mfma_f32_16x16x16_bf16)
DEV f32x4 mfma16(bf16x4 a, bf16x4 b, f32x4 c) {
  return __builtin_amdgcn_mfma_f32_16x16x16_bf16(a, b, c, 0, 0, 0);
}
#elif __has_builtin(__builtin_amdgcn_mfma_f32_16x16x16bf16_1k)
typedef short s16x4 __attribute__((ext_vector_type(4)));
DEV f32x4 mfma16(bf16x4 a, bf16x4 b, f32x4 c) {
  union U { bf16x4 h; s16x4 s; };
  U ua, ub; ua.h = a; ub.h = b;
  return __builtin_amdgcn_mfma_f32_16x16x16bf16_1k(ua.s, ub.s, c, 0, 0, 0);
}
#else
DEV f32x4 mfma16(bf16x4 a, bf16x4 b, f32x4 c) {
  asm("v_mfma_f32_16x16x16_bf16 %0, %1, %2, %0" : "+v"(c) : "v"(a), "v"(b));
  return c;
}
#endif

DEV void gload_lds16(const void* g, void* l) {
  __builtin_amdgcn_global_load_lds(
      (const __attribute__((address_space(1))) void*)g,
      (__attribute__((address_space(3))) void*)l, 16, 0, 0);
}

// ---------------- fp32 -> bf16 conversion (segmented: up to 4 tensors) ------
__global__ void __launch_bounds__(256) cvt_bf16_seg_kernel(
    const float* __restrict__ s0, const float* __restrict__ s1,
    const float* __restrict__ s2, const float* __restrict__ s3,
    unsigned short* __restrict__ out, int lg) {
  int i = blockIdx.x * blockDim.x + threadIdx.x;
  int seg = i >> lg, j = i & ((1 << lg) - 1);
  const float* src = seg == 0 ? s0 : seg == 1 ? s1 : seg == 2 ? s2 : s3;
  float4 v = reinterpret_cast<const float4*>(src)[j];
  ushort4 o;
  o.x = f2bf(v.x); o.y = f2bf(v.y); o.z = f2bf(v.z); o.w = f2bf(v.w);
  reinterpret_cast<ushort4*>(out)[i] = o;
}

// ---------------- GEMM: C[m][n] = (sum_k A[m][k]*W[n][k] + bias[n]) * scale ----
// A: [M][K] bf16 row-major, W: [N][K] bf16 row-major (i.e. X @ W^T)
// 128x128 tile, BK=32, 256 threads (4 waves, 2x2), 16 16x16x32 MFMA per
// wave per K-step. PIPELINED (attn-proven 2-phase idiom): double-buffered
// LDS; prologue stage; loop = {stage(next) -> MFMA(cur) -> vmcnt(0)+barrier}
// so the global->LDS latency hides under the current tile's MFMAs.
// BK=32 row stride = 64 B -> 4-slot XOR swizzle for conflict-free b128 frag
// reads: SOURCE col slot ^ (row&3) (LDS dest linear, global_load_lds
// constraint), read byte ^ ((l15&3)<<4). Both-sides, bijective.
// XCD swizzle: per-z-slice hw id -> (hw%8)*chunk + hw/8; each XCD gets 8
// consecutive m-panels x all n-blocks (A-panel 2MB + B 2MB fit its L2).
// QKV=true: blockIdx.z in {0,1,2} selects {Q,K,V} projection; V (z=2) is
// stored TRANSPOSED+kv-field-swapped (bits [5:4]<->[3:2] of s&63) to
// pre-compose attn's PV fragment layout into Vt. QKV=false: single f32
// linear-out GEMM (output projection).
template <bool QKV>
__global__ void __launch_bounds__(256) gemm_dbuf_kernel(
    const unsigned short* __restrict__ A0, const unsigned short* __restrict__ A1,
    const unsigned short* __restrict__ A2,
    const unsigned short* __restrict__ W0, const unsigned short* __restrict__ W1,
    const unsigned short* __restrict__ W2,
    const float* __restrict__ b0, const float* __restrict__ b1,
    const float* __restrict__ b2,
    void* __restrict__ C0, void* __restrict__ C1, void* __restrict__ C2,
    int M, int N, int K, float scale0) {
  __shared__ unsigned short lA[2][128 * 32];
  __shared__ unsigned short lB[2][128 * 32];
  const int t = threadIdx.x;
  const int wv = t >> 6, ln = t & 63;
  const int l15 = ln & 15, lhi = ln >> 4;

  const unsigned short* A; const unsigned short* W;
  const float* bias; void* Cout; float scale; int mode;
  if (QKV) {
    const int z = blockIdx.z;
    A = z == 0 ? A0 : z == 1 ? A1 : A2;
    W = z == 0 ? W0 : z == 1 ? W1 : W2;
    bias = z == 0 ? b0 : z == 1 ? b1 : b2;
    Cout = z == 0 ? C0 : z == 1 ? C1 : C2;
    scale = z == 0 ? scale0 : 1.0f;
    mode = z == 2 ? 2 : 1;
  } else {
    A = A0; W = W0; bias = b0; Cout = C0; scale = scale0; mode = 0;
  }

  // XCD-chunked remap (bijective; per-slice grid = 512, multiple of 8)
  const int nwg = gridDim.x * gridDim.y;
  const int hw = blockIdx.y * gridDim.x + blockIdx.x;
  const int chunk = nwg >> 3;
  const int swzid = (hw & 7) * chunk + (hw >> 3);
  const int m0 = (swzid / gridDim.x) * 128, n0 = (swzid % gridDim.x) * 128;
  const int wr = wv >> 1, wc = wv & 1;
  const int swzR = (l15 & 3) << 4; // frag-read byte XOR (row&3 == l15&3)

  // staging: thread t loads rows (t>>2) and (t>>2)+64, 16B each, source col
  // pre-swizzled (both rows share row&3, so one swizzled col serves both)
  const int rowA = t >> 2;
  const int colS = ((t & 3) ^ (rowA & 3)) * 8;
  const unsigned short* aS = A + (size_t)(m0 + rowA) * K + colS;
  const unsigned short* wS = W + (size_t)(n0 + rowA) * K + colS;
  const size_t rstep = (size_t)64 * K;
  const int d0 = t * 16, d1 = 4096 + t * 16;

  f32x4 acc[4][4] = {};

#define GSTAGE(bi, k0_)                                        \
  do {                                                         \
    gload_lds16(aS + (k0_), (char*)lA[bi] + d0);               \
    gload_lds16(aS + rstep + (k0_), (char*)lA[bi] + d1);       \
    gload_lds16(wS + (k0_), (char*)lB[bi] + d0);               \
    gload_lds16(wS + rstep + (k0_), (char*)lB[bi] + d1);       \
  } while (0)

  GSTAGE(0, 0);
  asm volatile("s_waitcnt vmcnt(0)" ::: "memory");
  __builtin_amdgcn_s_barrier();
  __builtin_amdgcn_sched_barrier(0);

  const int NK = K >> 5;
  for (int tk = 0; tk < NK; ++tk) {
    const int cur = tk & 1;
    if (tk + 1 < NK) GSTAGE(cur ^ 1, (tk + 1) * 32); // prefetch next K-tile

    bf16x8 af[4], bfr[4];
#pragma unroll
    for (int i = 0; i < 4; ++i)
      af[i] = *reinterpret_cast<const bf16x8*>(
          (char*)lA[cur] + (((wr * 64 + i * 16 + l15) * 64 + lhi * 16) ^ swzR));
#pragma unroll
    for (int j = 0; j < 4; ++j)
      bfr[j] = *reinterpret_cast<const bf16x8*>(
          (char*)lB[cur] + (((wc * 64 + j * 16 + l15) * 64 + lhi * 16) ^ swzR));
#pragma unroll
    for (int i = 0; i < 4; ++i)
#pragma unroll
      for (int j = 0; j < 4; ++j)
        acc[i][j] = __builtin_amdgcn_mfma_f32_16x16x32_bf16(af[i], bfr[j], acc[i][j], 0, 0, 0);

    asm volatile("s_waitcnt vmcnt(0)" ::: "memory");
    __builtin_amdgcn_s_barrier();
    __builtin_amdgcn_sched_barrier(0);
  }
#undef GSTAGE

#pragma unroll
  for (int i = 0; i < 4; ++i)
#pragma unroll
    for (int j = 0; j < 4; ++j) {
      int n = n0 + wc * 64 + j * 16 + l15;
      float bv = bias[n];
      if (QKV && mode == 2) {
        int mb = m0 + wr * 64 + i * 16 + lhi * 4; // 4 consecutive m = consecutive s
        int sl = mb & (Sc - 1);
        // field-swap bits [5:4]<->[3:2] (low 2 bits untouched -> ushort4 ok)
        int pl = (sl & ~60) | ((sl & 48) >> 2) | ((sl & 12) << 2);
        ushort4 ov;
        ov.x = f2bf((acc[i][j][0] + bv) * scale);
        ov.y = f2bf((acc[i][j][1] + bv) * scale);
        ov.z = f2bf((acc[i][j][2] + bv) * scale);
        ov.w = f2bf((acc[i][j][3] + bv) * scale);
        *reinterpret_cast<ushort4*>((unsigned short*)Cout +
            ((size_t)(mb >> 11) * Dc + n) * Sc + pl) = ov;
      } else {
#pragma unroll
        for (int jj = 0; jj < 4; ++jj) {
          int m = m0 + wr * 64 + i * 16 + lhi * 4 + jj;
          float v = (acc[i][j][jj] + bv) * scale;
          if (QKV)
            ((unsigned short*)Cout)[(size_t)m * N + n] = f2bf(v);
          else
            ((float*)Cout)[(size_t)m * N + n] = v;
        }
      }
    }
}

// ---------------- Flash attention ----------------
// Q prescaled by log2(e)/sqrt(DK) (softmax in exp2 domain).
// Q/K/X: [B*S][D] bf16; head h = columns [h*64, h*64+64).
// Vt: [B*D][S] bf16, kv-field-swapped within each 64-block (see GEMM).
// Block = (b, h, 128 q-rows); 8 waves x 16 q-rows each.
// __launch_bounds__(512, 4): 128-VGPR cap. (512,8) forced a 64-VGPR cap and
// spilled the accumulators to scratch -> 4.8x FETCH_SIZE, 2x slower (R3).
// Double-buffered K/V^T LDS tiles; prefetch BEFORE compute; one
// vmcnt(0)+s_barrier per tile. LDS = 32 KB.
// Swapped QK^T (x32): sacc[ct][jj] = S[kv=ct*16+lhi*4+jj][q-row l15].
// PV via 16x16x16 MFMA: A-frag k = lhi*4+i == sacc's kv granularity, so
// P = exp2(sacc - m) feeds PV DIRECTLY from registers. The field-swapped Vt
// layout makes each ct-PAIR's B-fragments one contiguous swizzled 16B run.
// Row sums via ones-MFMA (same layout as xacc -> no shuffles anywhere).
// Defer-max (THR=8): per-lane check; cross-lane reduce only on rescale tiles.
__global__ void __launch_bounds__(512, 4) attn_kernel(
    const unsigned short* __restrict__ Q, const unsigned short* __restrict__ Kk,
    const unsigned short* __restrict__ Vt, unsigned short* __restrict__ X) {
  __shared__ unsigned short lK[2][64 * 64];   // [kv][dk], XOR-swizzled (both-sides)
  __shared__ unsigned short lVT[2][64 * 64];  // [dk][swapped-kv], XOR-swizzled
  const int t = threadIdx.x;
  const int wv = t >> 6, ln = t & 63;
  const int l15 = ln & 15, lhi = ln >> 4;
  const int q0 = blockIdx.x * 128;
  const int h = blockIdx.y, b = blockIdx.z;
  const size_t base = (size_t)b * Sc * Dc;
  const int hoff = h * DKc;

  bf16x8 qf[2];
  {
    const unsigned short* qp = Q + base + (size_t)(q0 + wv * 16 + l15) * Dc + hoff + lhi * 8;
    qf[0] = *reinterpret_cast<const bf16x8*>(qp);
    qf[1] = *reinterpret_cast<const bf16x8*>(qp + 32);
  }

  // staging: 512 threads x 16B = one full 64x64 bf16 tile per buffer.
  // LDS dest LINEAR (global_load_lds constraint); swizzle applied on SOURCE
  // col. (For Vt the fragment-perm is already in the global layout, so the
  // staging address math is identical for K and Vt.)
  const int e0 = t * 8;
  const int r0 = e0 >> 6, c0 = (e0 & 63) ^ ((r0 & 7) << 3);
  const unsigned short* kS0 = Kk + base + (size_t)r0 * Dc + hoff + c0;
  const unsigned short* vS0 = Vt + ((size_t)b * Dc + hoff + r0) * Sc + c0;

  float mrow = -1e30f;            // running max for q-row l15 (x4 replicated)
  f32x4 xacc[4] = {};             // out rows lhi*4+jj, cols dt*16+l15
  f32x4 lsum = {};                // row sums for rows lhi*4+jj (ones-MFMA)
  const int swzK = (l15 & 7) << 4;

  bf16x4 ones4;
#pragma unroll
  for (int i = 0; i < 4; ++i) ones4[i] = (bf16_t)1.0f;

#define STAGE(bi, kv0_)                                                    \
  do {                                                                     \
    gload_lds16(kS0 + (size_t)(kv0_)*Dc, (char*)lK[bi] + e0 * 2);          \
    gload_lds16(vS0 + (kv0_), (char*)lVT[bi] + e0 * 2);                    \
  } while (0)

  STAGE(0, 0);
  asm volatile("s_waitcnt vmcnt(0)" ::: "memory");
  __builtin_amdgcn_s_barrier();
  __builtin_amdgcn_sched_barrier(0);

  for (int tt = 0; tt < Sc / 64; ++tt) {
    const int cur = tt & 1;
    if (tt + 1 < Sc / 64) STAGE(cur ^ 1, (tt + 1) * 64); // prefetch next tile

    const unsigned short* K_ = lK[cur];
    const unsigned short* VT_ = lVT[cur];

    // swapped QK^T: sacc[ct][jj] = S[kv0 + ct*16 + lhi*4 + jj][q-row l15]
    f32x4 sacc[4];
#pragma unroll
    for (int ct = 0; ct < 4; ++ct) {
      f32x4 z = {};
#pragma unroll
      for (int kk = 0; kk < 2; ++kk) {
        bf16x8 kf = *reinterpret_cast<const bf16x8*>(
            (const char*)K_ + (((ct * 16 + l15) * 128 + kk * 64 + lhi * 16) ^ swzK));
        z = __builtin_amdgcn_mfma_f32_16x16x32_bf16(kf, qf[kk], z, 0, 0, 0);
      }
      sacc[ct] = z;
    }

    // per-lane max over this lane's 16 scores (no cross-lane yet)
    float mt = fmaxf(fmaxf(sacc[0][0], sacc[0][1]), fmaxf(sacc[0][2], sacc[0][3]));
#pragma unroll
    for (int ct = 1; ct < 4; ++ct)
      mt = fmaxf(mt,
          fmaxf(fmaxf(sacc[ct][0], sacc[ct][1]), fmaxf(sacc[ct][2], sacc[ct][3])));

    // defer-max: rescale only when some lane's max grew past threshold.
    // Stale m keeps P <= 2^8 = 256 — fine in f32 accum / bf16 P.
    if (__any(mt > mrow + 8.0f)) {
      float mtr = fmaxf(mt, __shfl_xor(mt, 16));
      mtr = fmaxf(mtr, __shfl_xor(mtr, 32)); // row max (lanes sharing l15)
      float mnew = fmaxf(mrow, mtr);
      float corr = fexp2(mrow - mnew);
      mrow = mnew;
#pragma unroll
      for (int jj = 0; jj < 4; ++jj) {
        float cO = __shfl(corr, lhi * 4 + jj); // corr of q-row lhi*4+jj
        lsum[jj] *= cO;
#pragma unroll
        for (int dt = 0; dt < 4; ++dt) xacc[dt][jj] *= cO;
      }
    }

    // P fragments in-register: pa[ct] IS the x16 A-fragment for kv-chunk ct
    bf16x4 pa[4];
#pragma unroll
    for (int ct = 0; ct < 4; ++ct)
#pragma unroll
      for (int jj = 0; jj < 4; ++jj)
        pa[ct][jj] = (bf16_t)fexp2(sacc[ct][jj] - mrow);

    // row-sum via ones-MFMA
#pragma unroll
    for (int ct = 0; ct < 4; ++ct) lsum = mfma16(pa[ct], ones4, lsum);

    // PV: one b128 per (dt, ct-pair) holds BOTH x16 B-fragments
#pragma unroll
    for (int dt = 0; dt < 4; ++dt) {
#pragma unroll
      for (int sel = 0; sel < 2; ++sel) {
        bf16x8 vb2 = *reinterpret_cast<const bf16x8*>(
            (const char*)VT_ + (((dt * 16 + l15) * 128 + lhi * 32 + sel * 16) ^ swzK));
        bf16x4 vlo = __builtin_shufflevector(vb2, vb2, 0, 1, 2, 3);
        bf16x4 vhi = __builtin_shufflevector(vb2, vb2, 4, 5, 6, 7);
        xacc[dt] = mfma16(pa[2 * sel + 0], vlo, xacc[dt]);
        xacc[dt] = mfma16(pa[2 * sel + 1], vhi, xacc[dt]);
      }
    }

    // single drain+barrier per tile
    asm volatile("s_waitcnt vmcnt(0)" ::: "memory");
    __builtin_amdgcn_s_barrier();
    __builtin_amdgcn_sched_barrier(0);
  }
#undef STAGE

  // lsum[jj] is already the row sum for output row lhi*4+jj — no shuffles.
  float iO[4];
#pragma unroll
  for (int jj = 0; jj < 4; ++jj) iO[jj] = 1.0f / lsum[jj];

  unsigned short* xp = X + base + (size_t)(q0 + wv * 16) * Dc + hoff;
#pragma unroll
  for (int dt = 0; dt < 4; ++dt)
#pragma unroll
    for (int jj = 0; jj < 4; ++jj) {
      int r = lhi * 4 + jj;
      xp[(size_t)r * Dc + dt * 16 + l15] = f2bf(xacc[dt][jj] * iO[jj]);
    }
}

// ---------------- launch ----------------
extern "C" void kernel_launch(void* const* d_in, const int* in_sizes, int n_in,
                              void* d_out, int out_size, void* d_ws, size_t ws_size,
                              hipStream_t stream) {
  const float* query = (const float*)d_in[0];
  const float* key   = (const float*)d_in[1];
  const float* value = (const float*)d_in[2];
  const float* Wq = (const float*)d_in[3];
  const float* bq = (const float*)d_in[4];
  const float* Wk = (const float*)d_in[5];
  const float* bk = (const float*)d_in[6];
  const float* Wv = (const float*)d_in[7];
  const float* bv = (const float*)d_in[8];
  const float* Wo = (const float*)d_in[9];
  const float* bo = (const float*)d_in[10];

  const size_t NBS = (size_t)Mrows * Dc; // 8388608
  const size_t NW  = (size_t)Dc * Dc;    // 1048576
  unsigned short* bQin = (unsigned short*)d_ws;
  unsigned short* bKin = bQin + NBS;
  unsigned short* bVin = bKin + NBS;
  unsigned short* bWq  = bVin + NBS;
  unsigned short* bWk  = bWq + NW;
  unsigned short* bWv  = bWk + NW;
  unsigned short* bWo  = bWv + NW;
  unsigned short* Qp   = bWo + NW;
  unsigned short* Kp   = Qp + NBS;
  unsigned short* Vtp  = Kp + NBS; // V projection, TRANSPOSED + field-swapped
  unsigned short* Xp   = Vtp + NBS;

  // inputs: 3 contiguous segments (bQin,bKin,bVin); lg = log2(NBS/4) = 21
  cvt_bf16_seg_kernel<<<(int)(3 * NBS / 1024), 256, 0, stream>>>(
      query, key, value, value, bQin, 21);
  // weights: 4 contiguous segments (bWq..bWo); lg = log2(NW/4) = 18
  cvt_bf16_seg_kernel<<<(int)(4 * NW / 1024), 256, 0, stream>>>(
      Wq, Wk, Wv, Wo, bWq, 18);

  // fused Q/K/V projections: z selects; Q prescale folds 1/sqrt(DK) AND
  // log2(e) (attn softmax runs in exp2 domain)
  gemm_dbuf_kernel<true><<<dim3(Dc / 128, Mrows / 128, 3), 256, 0, stream>>>(
      bQin, bKin, bVin, bWq, bWk, bWv, bq, bk, bv, Qp, Kp, Vtp,
      Mrows, Dc, Dc, 0.125f * 1.44269504088896340736f);

  attn_kernel<<<dim3(Sc / 128, Hc, Bc), 512, 0, stream>>>(Qp, Kp, Vtp, Xp);

  gemm_dbuf_kernel<false><<<dim3(Dc / 128, Mrows / 128, 1), 256, 0, stream>>>(
      Xp, nullptr, nullptr, bWo, nullptr, nullptr, bo, nullptr, nullptr,
      d_out, nullptr, nullptr, Mrows, Dc, Dc, 1.0f);
}

// Round 7
// 232.679 us; speedup vs baseline: 1.6229x; 1.0097x over previous
//
#include <hip/hip_runtime.h>
#include <stdint.h>

#define DEV static __device__ __forceinline__

typedef __bf16 bf16_t;
typedef bf16_t bf16x8 __attribute__((ext_vector_type(8)));
typedef bf16_t bf16x4 __attribute__((ext_vector_type(4)));
typedef float f32x4 __attribute__((ext_vector_type(4)));

static constexpr int Bc = 4, Sc = 2048, Dc = 1024, Hc = 16, DKc = 64;
static constexpr int Mrows = Bc * Sc; // 8192

DEV unsigned short f2bf(float f) {
  unsigned int u = __float_as_uint(f);
  u += 0x7fffu + ((u >> 16) & 1u);
  return (unsigned short)(u >> 16);
}

DEV float fexp2(float x) {
#if __has_builtin(__builtin_amdgcn_exp2f)
  return __builtin_amdgcn_exp2f(x); // single v_exp_f32
#else
  return exp2f(x);
#endif
}

// 16x16x16 bf16 MFMA (K=16): A-frag k-granularity = lhi*4 -- matches the
// swapped-QK^T D-layout exactly, so P feeds PV straight from registers.
#if __has_builtin(__builtin_amdgcn_mfma_f32_16x16x16_bf16)
DEV f32x4 mfma16(bf16x4 a, bf16x4 b, f32x4 c) {
  return __builtin_amdgcn_mfma_f32_16x16x16_bf16(a, b, c, 0, 0, 0);
}
#elif __has_builtin(__builtin_amdgcn_mfma_f32_16x16x16bf16_1k)
typedef short s16x4 __attribute__((ext_vector_type(4)));
DEV f32x4 mfma16(bf16x4 a, bf16x4 b, f32x4 c) {
  union U { bf16x4 h; s16x4 s; };
  U ua, ub; ua.h = a; ub.h = b;
  return __builtin_amdgcn_mfma_f32_16x16x16bf16_1k(ua.s, ub.s, c, 0, 0, 0);
}
#else
DEV f32x4 mfma16(bf16x4 a, bf16x4 b, f32x4 c) {
  asm("v_mfma_f32_16x16x16_bf16 %0, %1, %2, %0" : "+v"(c) : "v"(a), "v"(b));
  return c;
}
#endif

DEV void gload_lds16(const void* g, void* l) {
  __builtin_amdgcn_global_load_lds(
      (const __attribute__((address_space(1))) void*)g,
      (__attribute__((address_space(3))) void*)l, 16, 0, 0);
}

// ---------------- fp32 -> bf16 conversion (segmented: up to 4 tensors) ------
__global__ void __launch_bounds__(256) cvt_bf16_seg_kernel(
    const float* __restrict__ s0, const float* __restrict__ s1,
    const float* __restrict__ s2, const float* __restrict__ s3,
    unsigned short* __restrict__ out, int lg) {
  int i = blockIdx.x * blockDim.x + threadIdx.x;
  int seg = i >> lg, j = i & ((1 << lg) - 1);
  const float* src = seg == 0 ? s0 : seg == 1 ? s1 : seg == 2 ? s2 : s3;
  float4 v = reinterpret_cast<const float4*>(src)[j];
  ushort4 o;
  o.x = f2bf(v.x); o.y = f2bf(v.y); o.z = f2bf(v.z); o.w = f2bf(v.w);
  reinterpret_cast<ushort4*>(out)[i] = o;
}

// ---------------- GEMM: C[m][n] = (sum_k A[m][k]*W[n][k] + bias[n]) * scale ----
// A: [M][K] bf16 row-major, W: [N][K] bf16 row-major (i.e. X @ W^T)
// 128x128 tile, BK=32, 256 threads (4 waves, 2x2), 16 16x16x32 MFMA per
// wave per K-step.
// T4 COUNTED-VMCNT PIPELINE (m218: counted-vs-drain0 = +38%): 3 LDS buffers,
// depth-2 prefetch, ONE barrier per K-step, NEVER vmcnt(0) in the loop.
//   iter t: vmcnt(4)            -- t's 4 loads done; t+1's 4 may stay in flight
//           s_barrier           -- all waves' t-loads have landed in LDS
//           GSTAGE(buf[(t+2)%3])-- overwrites buf last read at t-1: safe, the
//                                  top barrier proves every wave finished t-1
//           MFMA(buf[t%3])
// Last iteration uses vmcnt(0) (nothing newer in flight to exclude).
// BK=32 row stride = 64 B -> 4-slot XOR swizzle for conflict-free b128 frag
// reads: SOURCE col slot ^ (row&3) (LDS dest linear, global_load_lds
// constraint), read byte ^ ((l15&3)<<4). Both-sides, bijective.
// XCD swizzle: per-z-slice hw id -> (hw%8)*chunk + hw/8.
// QKV=true: blockIdx.z in {0,1,2} selects {Q,K,V}; V (z=2) stored
// TRANSPOSED+kv-field-swapped. QKV=false: f32 linear out (output proj).
template <bool QKV>
__global__ void __launch_bounds__(256) gemm_dbuf_kernel(
    const unsigned short* __restrict__ A0, const unsigned short* __restrict__ A1,
    const unsigned short* __restrict__ A2,
    const unsigned short* __restrict__ W0, const unsigned short* __restrict__ W1,
    const unsigned short* __restrict__ W2,
    const float* __restrict__ b0, const float* __restrict__ b1,
    const float* __restrict__ b2,
    void* __restrict__ C0, void* __restrict__ C1, void* __restrict__ C2,
    int M, int N, int K, float scale0) {
  __shared__ unsigned short lA[3][128 * 32];
  __shared__ unsigned short lB[3][128 * 32];
  const int t = threadIdx.x;
  const int wv = t >> 6, ln = t & 63;
  const int l15 = ln & 15, lhi = ln >> 4;

  const unsigned short* A; const unsigned short* W;
  const float* bias; void* Cout; float scale; int mode;
  if (QKV) {
    const int z = blockIdx.z;
    A = z == 0 ? A0 : z == 1 ? A1 : A2;
    W = z == 0 ? W0 : z == 1 ? W1 : W2;
    bias = z == 0 ? b0 : z == 1 ? b1 : b2;
    Cout = z == 0 ? C0 : z == 1 ? C1 : C2;
    scale = z == 0 ? scale0 : 1.0f;
    mode = z == 2 ? 2 : 1;
  } else {
    A = A0; W = W0; bias = b0; Cout = C0; scale = scale0; mode = 0;
  }

  // XCD-chunked remap (bijective; per-slice grid = 512, multiple of 8)
  const int nwg = gridDim.x * gridDim.y;
  const int hw = blockIdx.y * gridDim.x + blockIdx.x;
  const int chunk = nwg >> 3;
  const int swzid = (hw & 7) * chunk + (hw >> 3);
  const int m0 = (swzid / gridDim.x) * 128, n0 = (swzid % gridDim.x) * 128;
  const int wr = wv >> 1, wc = wv & 1;
  const int swzR = (l15 & 3) << 4; // frag-read byte XOR (row&3 == l15&3)

  // staging: thread t loads rows (t>>2) and (t>>2)+64, 16B each, source col
  // pre-swizzled (both rows share row&3, so one swizzled col serves both)
  const int rowA = t >> 2;
  const int colS = ((t & 3) ^ (rowA & 3)) * 8;
  const unsigned short* aS = A + (size_t)(m0 + rowA) * K + colS;
  const unsigned short* wS = W + (size_t)(n0 + rowA) * K + colS;
  const size_t rstep = (size_t)64 * K;
  const int d0 = t * 16, d1 = 4096 + t * 16;

  f32x4 acc[4][4] = {};

#define GSTAGE(bi, k0_)                                        \
  do {                                                         \
    gload_lds16(aS + (k0_), (char*)lA[bi] + d0);               \
    gload_lds16(aS + rstep + (k0_), (char*)lA[bi] + d1);       \
    gload_lds16(wS + (k0_), (char*)lB[bi] + d0);               \
    gload_lds16(wS + rstep + (k0_), (char*)lB[bi] + d1);       \
  } while (0)

  GSTAGE(0, 0);
  GSTAGE(1, 32);

  const int NK = K >> 5; // 32
  int cur = 0, stg = 2;
  for (int tk = 0; tk < NK; ++tk) {
    if (tk == NK - 1)
      asm volatile("s_waitcnt vmcnt(0)" ::: "memory");
    else
      asm volatile("s_waitcnt vmcnt(4)" ::: "memory");
    __builtin_amdgcn_s_barrier();
    __builtin_amdgcn_sched_barrier(0);

    if (tk + 2 < NK) GSTAGE(stg, (tk + 2) * 32); // depth-2 prefetch

    bf16x8 af[4], bfr[4];
#pragma unroll
    for (int i = 0; i < 4; ++i)
      af[i] = *reinterpret_cast<const bf16x8*>(
          (char*)lA[cur] + (((wr * 64 + i * 16 + l15) * 64 + lhi * 16) ^ swzR));
#pragma unroll
    for (int j = 0; j < 4; ++j)
      bfr[j] = *reinterpret_cast<const bf16x8*>(
          (char*)lB[cur] + (((wc * 64 + j * 16 + l15) * 64 + lhi * 16) ^ swzR));
#pragma unroll
    for (int i = 0; i < 4; ++i)
#pragma unroll
      for (int j = 0; j < 4; ++j)
        acc[i][j] = __builtin_amdgcn_mfma_f32_16x16x32_bf16(af[i], bfr[j], acc[i][j], 0, 0, 0);

    cur = cur == 2 ? 0 : cur + 1;
    stg = stg == 2 ? 0 : stg + 1;
  }
#undef GSTAGE

#pragma unroll
  for (int i = 0; i < 4; ++i)
#pragma unroll
    for (int j = 0; j < 4; ++j) {
      int n = n0 + wc * 64 + j * 16 + l15;
      float bv = bias[n];
      if (QKV && mode == 2) {
        int mb = m0 + wr * 64 + i * 16 + lhi * 4; // 4 consecutive m = consecutive s
        int sl = mb & (Sc - 1);
        // field-swap bits [5:4]<->[3:2] (low 2 bits untouched -> ushort4 ok)
        int pl = (sl & ~60) | ((sl & 48) >> 2) | ((sl & 12) << 2);
        ushort4 ov;
        ov.x = f2bf((acc[i][j][0] + bv) * scale);
        ov.y = f2bf((acc[i][j][1] + bv) * scale);
        ov.z = f2bf((acc[i][j][2] + bv) * scale);
        ov.w = f2bf((acc[i][j][3] + bv) * scale);
        *reinterpret_cast<ushort4*>((unsigned short*)Cout +
            ((size_t)(mb >> 11) * Dc + n) * Sc + pl) = ov;
      } else {
#pragma unroll
        for (int jj = 0; jj < 4; ++jj) {
          int m = m0 + wr * 64 + i * 16 + lhi * 4 + jj;
          float v = (acc[i][j][jj] + bv) * scale;
          if (QKV)
            ((unsigned short*)Cout)[(size_t)m * N + n] = f2bf(v);
          else
            ((float*)Cout)[(size_t)m * N + n] = v;
        }
      }
    }
}

// ---------------- Flash attention ----------------
// Q prescaled by log2(e)/sqrt(DK) (softmax in exp2 domain).
// Q/K/X: [B*S][D] bf16; head h = columns [h*64, h*64+64).
// Vt: [B*D][S] bf16, kv-field-swapped within each 64-block (see GEMM).
// Block = (b, h, 128 q-rows); 8 waves x 16 q-rows each.
// __launch_bounds__(512, 4): 128-VGPR cap. (512,8) forced a 64-VGPR cap and
// spilled the accumulators to scratch -> 4.8x FETCH_SIZE, 2x slower (R3).
// T4 COUNTED-VMCNT PIPELINE (same as GEMM): 3 LDS buffer-pairs, depth-2
// prefetch, ONE barrier per kv-tile, vmcnt(2) in-loop (2 loads per STAGE),
// vmcnt(0) only on the last tile. Loads stay in flight across barriers.
// Swapped QK^T (x32): sacc[ct][jj] = S[kv=ct*16+lhi*4+jj][q-row l15].
// PV via 16x16x16 MFMA: A-frag k = lhi*4+i == sacc's kv granularity, so
// P = exp2(sacc - m) feeds PV DIRECTLY from registers. The field-swapped Vt
// layout makes each ct-PAIR's B-fragments one contiguous swizzled 16B run.
// Row sums via ones-MFMA (same layout as xacc -> no shuffles anywhere).
// Defer-max (THR=8): per-lane check; cross-lane reduce only on rescale tiles.
__global__ void __launch_bounds__(512, 4) attn_kernel(
    const unsigned short* __restrict__ Q, const unsigned short* __restrict__ Kk,
    const unsigned short* __restrict__ Vt, unsigned short* __restrict__ X) {
  __shared__ unsigned short lK[3][64 * 64];   // [kv][dk], XOR-swizzled (both-sides)
  __shared__ unsigned short lVT[3][64 * 64];  // [dk][swapped-kv], XOR-swizzled
  const int t = threadIdx.x;
  const int wv = t >> 6, ln = t & 63;
  const int l15 = ln & 15, lhi = ln >> 4;
  const int q0 = blockIdx.x * 128;
  const int h = blockIdx.y, b = blockIdx.z;
  const size_t base = (size_t)b * Sc * Dc;
  const int hoff = h * DKc;

  bf16x8 qf[2];
  {
    const unsigned short* qp = Q + base + (size_t)(q0 + wv * 16 + l15) * Dc + hoff + lhi * 8;
    qf[0] = *reinterpret_cast<const bf16x8*>(qp);
    qf[1] = *reinterpret_cast<const bf16x8*>(qp + 32);
  }

  // staging: 512 threads x 16B = one full 64x64 bf16 tile per buffer.
  // LDS dest LINEAR (global_load_lds constraint); swizzle applied on SOURCE
  // col. (For Vt the fragment-perm is already in the global layout, so the
  // staging address math is identical for K and Vt.)
  const int e0 = t * 8;
  const int r0 = e0 >> 6, c0 = (e0 & 63) ^ ((r0 & 7) << 3);
  const unsigned short* kS0 = Kk + base + (size_t)r0 * Dc + hoff + c0;
  const unsigned short* vS0 = Vt + ((size_t)b * Dc + hoff + r0) * Sc + c0;

  float mrow = -1e30f;            // running max for q-row l15 (x4 replicated)
  f32x4 xacc[4] = {};             // out rows lhi*4+jj, cols dt*16+l15
  f32x4 lsum = {};                // row sums for rows lhi*4+jj (ones-MFMA)
  const int swzK = (l15 & 7) << 4;

  bf16x4 ones4;
#pragma unroll
  for (int i = 0; i < 4; ++i) ones4[i] = (bf16_t)1.0f;

#define STAGE(bi, kv0_)                                                    \
  do {                                                                     \
    gload_lds16(kS0 + (size_t)(kv0_)*Dc, (char*)lK[bi] + e0 * 2);          \
    gload_lds16(vS0 + (kv0_), (char*)lVT[bi] + e0 * 2);                    \
  } while (0)

  STAGE(0, 0);
  STAGE(1, 64);

  const int NT = Sc / 64; // 32
  int cur = 0, stg = 2;
  for (int tt = 0; tt < NT; ++tt) {
    if (tt == NT - 1)
      asm volatile("s_waitcnt vmcnt(0)" ::: "memory");
    else
      asm volatile("s_waitcnt vmcnt(2)" ::: "memory");
    __builtin_amdgcn_s_barrier();
    __builtin_amdgcn_sched_barrier(0);

    if (tt + 2 < NT) STAGE(stg, (tt + 2) * 64); // depth-2 prefetch

    const unsigned short* K_ = lK[cur];
    const unsigned short* VT_ = lVT[cur];

    // swapped QK^T: sacc[ct][jj] = S[kv0 + ct*16 + lhi*4 + jj][q-row l15]
    f32x4 sacc[4];
#pragma unroll
    for (int ct = 0; ct < 4; ++ct) {
      f32x4 z = {};
#pragma unroll
      for (int kk = 0; kk < 2; ++kk) {
        bf16x8 kf = *reinterpret_cast<const bf16x8*>(
            (const char*)K_ + (((ct * 16 + l15) * 128 + kk * 64 + lhi * 16) ^ swzK));
        z = __builtin_amdgcn_mfma_f32_16x16x32_bf16(kf, qf[kk], z, 0, 0, 0);
      }
      sacc[ct] = z;
    }

    // per-lane max over this lane's 16 scores (no cross-lane yet)
    float mt = fmaxf(fmaxf(sacc[0][0], sacc[0][1]), fmaxf(sacc[0][2], sacc[0][3]));
#pragma unroll
    for (int ct = 1; ct < 4; ++ct)
      mt = fmaxf(mt,
          fmaxf(fmaxf(sacc[ct][0], sacc[ct][1]), fmaxf(sacc[ct][2], sacc[ct][3])));

    // defer-max: rescale only when some lane's max grew past threshold.
    // Stale m keeps P <= 2^8 = 256 — fine in f32 accum / bf16 P.
    if (__any(mt > mrow + 8.0f)) {
      float mtr = fmaxf(mt, __shfl_xor(mt, 16));
      mtr = fmaxf(mtr, __shfl_xor(mtr, 32)); // row max (lanes sharing l15)
      float mnew = fmaxf(mrow, mtr);
      float corr = fexp2(mrow - mnew);
      mrow = mnew;
#pragma unroll
      for (int jj = 0; jj < 4; ++jj) {
        float cO = __shfl(corr, lhi * 4 + jj); // corr of q-row lhi*4+jj
        lsum[jj] *= cO;
#pragma unroll
        for (int dt = 0; dt < 4; ++dt) xacc[dt][jj] *= cO;
      }
    }

    // P fragments in-register: pa[ct] IS the x16 A-fragment for kv-chunk ct
    bf16x4 pa[4];
#pragma unroll
    for (int ct = 0; ct < 4; ++ct)
#pragma unroll
      for (int jj = 0; jj < 4; ++jj)
        pa[ct][jj] = (bf16_t)fexp2(sacc[ct][jj] - mrow);

    // row-sum via ones-MFMA
#pragma unroll
    for (int ct = 0; ct < 4; ++ct) lsum = mfma16(pa[ct], ones4, lsum);

    // PV: one b128 per (dt, ct-pair) holds BOTH x16 B-fragments
#pragma unroll
    for (int dt = 0; dt < 4; ++dt) {
#pragma unroll
      for (int sel = 0; sel < 2; ++sel) {
        bf16x8 vb2 = *reinterpret_cast<const bf16x8*>(
            (const char*)VT_ + (((dt * 16 + l15) * 128 + lhi * 32 + sel * 16) ^ swzK));
        bf16x4 vlo = __builtin_shufflevector(vb2, vb2, 0, 1, 2, 3);
        bf16x4 vhi = __builtin_shufflevector(vb2, vb2, 4, 5, 6, 7);
        xacc[dt] = mfma16(pa[2 * sel + 0], vlo, xacc[dt]);
        xacc[dt] = mfma16(pa[2 * sel + 1], vhi, xacc[dt]);
      }
    }

    cur = cur == 2 ? 0 : cur + 1;
    stg = stg == 2 ? 0 : stg + 1;
  }
#undef STAGE

  // lsum[jj] is already the row sum for output row lhi*4+jj — no shuffles.
  float iO[4];
#pragma unroll
  for (int jj = 0; jj < 4; ++jj) iO[jj] = 1.0f / lsum[jj];

  unsigned short* xp = X + base + (size_t)(q0 + wv * 16) * Dc + hoff;
#pragma unroll
  for (int dt = 0; dt < 4; ++dt)
#pragma unroll
    for (int jj = 0; jj < 4; ++jj) {
      int r = lhi * 4 + jj;
      xp[(size_t)r * Dc + dt * 16 + l15] = f2bf(xacc[dt][jj] * iO[jj]);
    }
}

// ---------------- launch ----------------
extern "C" void kernel_launch(void* const* d_in, const int* in_sizes, int n_in,
                              void* d_out, int out_size, void* d_ws, size_t ws_size,
                              hipStream_t stream) {
  const float* query = (const float*)d_in[0];
  const float* key   = (const float*)d_in[1];
  const float* value = (const float*)d_in[2];
  const float* Wq = (const float*)d_in[3];
  const float* bq = (const float*)d_in[4];
  const float* Wk = (const float*)d_in[5];
  const float* bk = (const float*)d_in[6];
  const float* Wv = (const float*)d_in[7];
  const float* bv = (const float*)d_in[8];
  const float* Wo = (const float*)d_in[9];
  const float* bo = (const float*)d_in[10];

  const size_t NBS = (size_t)Mrows * Dc; // 8388608
  const size_t NW  = (size_t)Dc * Dc;    // 1048576
  unsigned short* bQin = (unsigned short*)d_ws;
  unsigned short* bKin = bQin + NBS;
  unsigned short* bVin = bKin + NBS;
  unsigned short* bWq  = bVin + NBS;
  unsigned short* bWk  = bWq + NW;
  unsigned short* bWv  = bWk + NW;
  unsigned short* bWo  = bWv + NW;
  unsigned short* Qp   = bWo + NW;
  unsigned short* Kp   = Qp + NBS;
  unsigned short* Vtp  = Kp + NBS; // V projection, TRANSPOSED + field-swapped
  unsigned short* Xp   = Vtp + NBS;

  // inputs: 3 contiguous segments (bQin,bKin,bVin); lg = log2(NBS/4) = 21
  cvt_bf16_seg_kernel<<<(int)(3 * NBS / 1024), 256, 0, stream>>>(
      query, key, value, value, bQin, 21);
  // weights: 4 contiguous segments (bWq..bWo); lg = log2(NW/4) = 18
  cvt_bf16_seg_kernel<<<(int)(4 * NW / 1024), 256, 0, stream>>>(
      Wq, Wk, Wv, Wo, bWq, 18);

  // fused Q/K/V projections: z selects; Q prescale folds 1/sqrt(DK) AND
  // log2(e) (attn softmax runs in exp2 domain)
  gemm_dbuf_kernel<true><<<dim3(Dc / 128, Mrows / 128, 3), 256, 0, stream>>>(
      bQin, bKin, bVin, bWq, bWk, bWv, bq, bk, bv, Qp, Kp, Vtp,
      Mrows, Dc, Dc, 0.125f * 1.44269504088896340736f);

  attn_kernel<<<dim3(Sc / 128, Hc, Bc), 512, 0, stream>>>(Qp, Kp, Vtp, Xp);

  gemm_dbuf_kernel<false><<<dim3(Dc / 128, Mrows / 128, 1), 256, 0, stream>>>(
      Xp, nullptr, nullptr, bWo, nullptr, nullptr, bo, nullptr, nullptr,
      d_out, nullptr, nullptr, Mrows, Dc, Dc, 1.0f);
}

// Round 8
// 228.798 us; speedup vs baseline: 1.6505x; 1.0170x over previous
//
#include <hip/hip_runtime.h>
#include <stdint.h>

#define DEV static __device__ __forceinline__

typedef __bf16 bf16_t;
typedef bf16_t bf16x8 __attribute__((ext_vector_type(8)));
typedef bf16_t bf16x4 __attribute__((ext_vector_type(4)));
typedef float f32x4 __attribute__((ext_vector_type(4)));

static constexpr int Bc = 4, Sc = 2048, Dc = 1024, Hc = 16, DKc = 64;
static constexpr int Mrows = Bc * Sc; // 8192

DEV unsigned short f2bf(float f) {
  unsigned int u = __float_as_uint(f);
  u += 0x7fffu + ((u >> 16) & 1u);
  return (unsigned short)(u >> 16);
}

DEV float fexp2(float x) {
#if __has_builtin(__builtin_amdgcn_exp2f)
  return __builtin_amdgcn_exp2f(x); // single v_exp_f32
#else
  return exp2f(x);
#endif
}

// 16x16x16 bf16 MFMA (K=16): A-frag k-granularity = lhi*4 -- matches the
// swapped-QK^T D-layout exactly, so P feeds PV straight from registers.
#if __has_builtin(__builtin_amdgcn_mfma_f32_16x16x16_bf16)
DEV f32x4 mfma16(bf16x4 a, bf16x4 b, f32x4 c) {
  return __builtin_amdgcn_mfma_f32_16x16x16_bf16(a, b, c, 0, 0, 0);
}
#elif __has_builtin(__builtin_amdgcn_mfma_f32_16x16x16bf16_1k)
typedef short s16x4 __attribute__((ext_vector_type(4)));
DEV f32x4 mfma16(bf16x4 a, bf16x4 b, f32x4 c) {
  union U { bf16x4 h; s16x4 s; };
  U ua, ub; ua.h = a; ub.h = b;
  return __builtin_amdgcn_mfma_f32_16x16x16bf16_1k(ua.s, ub.s, c, 0, 0, 0);
}
#else
DEV f32x4 mfma16(bf16x4 a, bf16x4 b, f32x4 c) {
  asm("v_mfma_f32_16x16x16_bf16 %0, %1, %2, %0" : "+v"(c) : "v"(a), "v"(b));
  return c;
}
#endif

DEV void gload_lds16(const void* g, void* l) {
  __builtin_amdgcn_global_load_lds(
      (const __attribute__((address_space(1))) void*)g,
      (__attribute__((address_space(3))) void*)l, 16, 0, 0);
}

// ---------------- fp32 -> bf16 conversion (segmented: up to 4 tensors) ------
__global__ void __launch_bounds__(256) cvt_bf16_seg_kernel(
    const float* __restrict__ s0, const float* __restrict__ s1,
    const float* __restrict__ s2, const float* __restrict__ s3,
    unsigned short* __restrict__ out, int lg) {
  int i = blockIdx.x * blockDim.x + threadIdx.x;
  int seg = i >> lg, j = i & ((1 << lg) - 1);
  const float* src = seg == 0 ? s0 : seg == 1 ? s1 : seg == 2 ? s2 : s3;
  float4 v = reinterpret_cast<const float4*>(src)[j];
  ushort4 o;
  o.x = f2bf(v.x); o.y = f2bf(v.y); o.z = f2bf(v.z); o.w = f2bf(v.w);
  reinterpret_cast<ushort4*>(out)[i] = o;
}

// ---------------- GEMM: C[m][n] = (sum_k A[m][k]*W[n][k] + bias[n]) * scale ----
// (unchanged from R7: T4 counted-vmcnt 3-buffer pipeline, BK=32, XCD swizzle)
template <bool QKV>
__global__ void __launch_bounds__(256) gemm_dbuf_kernel(
    const unsigned short* __restrict__ A0, const unsigned short* __restrict__ A1,
    const unsigned short* __restrict__ A2,
    const unsigned short* __restrict__ W0, const unsigned short* __restrict__ W1,
    const unsigned short* __restrict__ W2,
    const float* __restrict__ b0, const float* __restrict__ b1,
    const float* __restrict__ b2,
    void* __restrict__ C0, void* __restrict__ C1, void* __restrict__ C2,
    int M, int N, int K, float scale0) {
  __shared__ unsigned short lA[3][128 * 32];
  __shared__ unsigned short lB[3][128 * 32];
  const int t = threadIdx.x;
  const int wv = t >> 6, ln = t & 63;
  const int l15 = ln & 15, lhi = ln >> 4;

  const unsigned short* A; const unsigned short* W;
  const float* bias; void* Cout; float scale; int mode;
  if (QKV) {
    const int z = blockIdx.z;
    A = z == 0 ? A0 : z == 1 ? A1 : A2;
    W = z == 0 ? W0 : z == 1 ? W1 : W2;
    bias = z == 0 ? b0 : z == 1 ? b1 : b2;
    Cout = z == 0 ? C0 : z == 1 ? C1 : C2;
    scale = z == 0 ? scale0 : 1.0f;
    mode = z == 2 ? 2 : 1;
  } else {
    A = A0; W = W0; bias = b0; Cout = C0; scale = scale0; mode = 0;
  }

  const int nwg = gridDim.x * gridDim.y;
  const int hw = blockIdx.y * gridDim.x + blockIdx.x;
  const int chunk = nwg >> 3;
  const int swzid = (hw & 7) * chunk + (hw >> 3);
  const int m0 = (swzid / gridDim.x) * 128, n0 = (swzid % gridDim.x) * 128;
  const int wr = wv >> 1, wc = wv & 1;
  const int swzR = (l15 & 3) << 4;

  const int rowA = t >> 2;
  const int colS = ((t & 3) ^ (rowA & 3)) * 8;
  const unsigned short* aS = A + (size_t)(m0 + rowA) * K + colS;
  const unsigned short* wS = W + (size_t)(n0 + rowA) * K + colS;
  const size_t rstep = (size_t)64 * K;
  const int d0 = t * 16, d1 = 4096 + t * 16;

  f32x4 acc[4][4] = {};

#define GSTAGE(bi, k0_)                                        \
  do {                                                         \
    gload_lds16(aS + (k0_), (char*)lA[bi] + d0);               \
    gload_lds16(aS + rstep + (k0_), (char*)lA[bi] + d1);       \
    gload_lds16(wS + (k0_), (char*)lB[bi] + d0);               \
    gload_lds16(wS + rstep + (k0_), (char*)lB[bi] + d1);       \
  } while (0)

  GSTAGE(0, 0);
  GSTAGE(1, 32);

  const int NK = K >> 5; // 32
  int cur = 0, stg = 2;
  for (int tk = 0; tk < NK; ++tk) {
    if (tk == NK - 1)
      asm volatile("s_waitcnt vmcnt(0)" ::: "memory");
    else
      asm volatile("s_waitcnt vmcnt(4)" ::: "memory");
    __builtin_amdgcn_s_barrier();
    __builtin_amdgcn_sched_barrier(0);

    if (tk + 2 < NK) GSTAGE(stg, (tk + 2) * 32);

    bf16x8 af[4], bfr[4];
#pragma unroll
    for (int i = 0; i < 4; ++i)
      af[i] = *reinterpret_cast<const bf16x8*>(
          (char*)lA[cur] + (((wr * 64 + i * 16 + l15) * 64 + lhi * 16) ^ swzR));
#pragma unroll
    for (int j = 0; j < 4; ++j)
      bfr[j] = *reinterpret_cast<const bf16x8*>(
          (char*)lB[cur] + (((wc * 64 + j * 16 + l15) * 64 + lhi * 16) ^ swzR));
#pragma unroll
    for (int i = 0; i < 4; ++i)
#pragma unroll
      for (int j = 0; j < 4; ++j)
        acc[i][j] = __builtin_amdgcn_mfma_f32_16x16x32_bf16(af[i], bfr[j], acc[i][j], 0, 0, 0);

    cur = cur == 2 ? 0 : cur + 1;
    stg = stg == 2 ? 0 : stg + 1;
  }
#undef GSTAGE

#pragma unroll
  for (int i = 0; i < 4; ++i)
#pragma unroll
    for (int j = 0; j < 4; ++j) {
      int n = n0 + wc * 64 + j * 16 + l15;
      float bv = bias[n];
      if (QKV && mode == 2) {
        int mb = m0 + wr * 64 + i * 16 + lhi * 4;
        int sl = mb & (Sc - 1);
        int pl = (sl & ~60) | ((sl & 48) >> 2) | ((sl & 12) << 2);
        ushort4 ov;
        ov.x = f2bf((acc[i][j][0] + bv) * scale);
        ov.y = f2bf((acc[i][j][1] + bv) * scale);
        ov.z = f2bf((acc[i][j][2] + bv) * scale);
        ov.w = f2bf((acc[i][j][3] + bv) * scale);
        *reinterpret_cast<ushort4*>((unsigned short*)Cout +
            ((size_t)(mb >> 11) * Dc + n) * Sc + pl) = ov;
      } else {
#pragma unroll
        for (int jj = 0; jj < 4; ++jj) {
          int m = m0 + wr * 64 + i * 16 + lhi * 4 + jj;
          float v = (acc[i][j][jj] + bv) * scale;
          if (QKV)
            ((unsigned short*)Cout)[(size_t)m * N + n] = f2bf(v);
          else
            ((float*)Cout)[(size_t)m * N + n] = v;
        }
      }
    }
}

// ---------------- Flash attention ----------------
// Q prescaled by log2(e)/sqrt(DK) (softmax in exp2 domain).
// Q/K/X: [B*S][D] bf16; Vt: [B*D][S] bf16, kv-field-swapped per 64-block.
// Block = (b, h, 128 q-rows); 8 waves x 16 q-rows each.
// R8 interior rework (interior-bound: 4 staging variants all 114.5us):
//  * KVBLK=128: two 64-kv subtiles per barrier -> barriers 32->16.
//    2 double-buffers (64KB LDS, 2 blocks/CU = measured residency anyway),
//    R1-proven drain-mode: stage-next BEFORE compute, vmcnt(0)+barrier after.
//  * -mrow FOLDED INTO QK^T ACCUMULATOR INIT (MFMA C-in = -mrow): sacc comes
//    out rebased (S - mrow); deletes 16 v_sub/tile; defer check is mt > 8.
//    nm starts 0 (not -1e30): the __any gate keeps sacc_rel <= 8 whenever
//    no rescale fires, so P <= 2^8 invariant holds from tile 0.
//  * rescale branch (rare): per-row mtr_eff = max(rowmax,0) replicates the
//    old per-row max(mrow, mtr) semantics; explicit 32 subs only here.
//  * max3-shaped reduction tree; s_setprio(1) around both MFMA clusters.
// PV via 16x16x16 MFMA from registers (pa = P fragment directly).
// Row sums via ones-MFMA (same layout as xacc -> no shuffles anywhere).
__global__ void __launch_bounds__(512, 4) attn_kernel(
    const unsigned short* __restrict__ Q, const unsigned short* __restrict__ Kk,
    const unsigned short* __restrict__ Vt, unsigned short* __restrict__ X) {
  __shared__ unsigned short lK[2][128 * 64];  // [kv][dk], XOR-swizzled
  __shared__ unsigned short lVT[2][64 * 128]; // [dk][swapped-kv], XOR-swizzled
  const int t = threadIdx.x;
  const int wv = t >> 6, ln = t & 63;
  const int l15 = ln & 15, lhi = ln >> 4;
  const int q0 = blockIdx.x * 128;
  const int h = blockIdx.y, b = blockIdx.z;
  const size_t base = (size_t)b * Sc * Dc;
  const int hoff = h * DKc;

  bf16x8 qf[2];
  {
    const unsigned short* qp = Q + base + (size_t)(q0 + wv * 16 + l15) * Dc + hoff + lhi * 8;
    qf[0] = *reinterpret_cast<const bf16x8*>(qp);
    qf[1] = *reinterpret_cast<const bf16x8*>(qp + 32);
  }

  // K staging (per thread, chunk c in {0,1}): dest byte c*8192 + t*16;
  //   elem = c*4096 + t*8 -> kv-row = c*64 + (t>>3), col = (t&7)*8.
  //   Source col pre-swizzled ^((kvrow&7)<<3); (t>>3)&7 same for both c.
  const int kvr = t >> 3;
  const int kcol = ((t & 7) * 8) ^ ((kvr & 7) << 3);
  const unsigned short* kS = Kk + base + (size_t)kvr * Dc + hoff + kcol;
  // V^T staging: dest byte c*8192 + t*16; elem -> dk = c*32 + (t>>4),
  //   kv-inner = (t&15)*8, source kv pre-swizzled ^((dk&7)<<3) (32%8==0).
  const int vdk = t >> 4;
  const int vkv = ((t & 15) * 8) ^ ((vdk & 7) << 3);
  const unsigned short* vS = Vt + ((size_t)b * Dc + hoff + vdk) * Sc + vkv;

  float nm = 0.f;       // nm = -mrow for q-row l15 (x4 replicated)
  f32x4 xacc[4] = {};   // out rows lhi*4+jj, cols dt*16+l15
  f32x4 lsum = {};      // row sums for rows lhi*4+jj (ones-MFMA)
  const int swzK = (l15 & 7) << 4;

  bf16x4 ones4;
#pragma unroll
  for (int i = 0; i < 4; ++i) ones4[i] = (bf16_t)1.0f;

#define DSTAGE(bi, kv0_)                                                        \
  do {                                                                          \
    gload_lds16(kS + (size_t)(kv0_)*Dc, (char*)lK[bi] + t * 16);                \
    gload_lds16(kS + (size_t)((kv0_) + 64) * Dc, (char*)lK[bi] + 8192 + t * 16);\
    gload_lds16(vS + (kv0_), (char*)lVT[bi] + t * 16);                          \
    gload_lds16(vS + (size_t)32 * Sc + (kv0_), (char*)lVT[bi] + 8192 + t * 16); \
  } while (0)

  DSTAGE(0, 0);
  asm volatile("s_waitcnt vmcnt(0)" ::: "memory");
  __builtin_amdgcn_s_barrier();
  __builtin_amdgcn_sched_barrier(0);

  const int NT2 = Sc / 128; // 16
  for (int tt = 0; tt < NT2; ++tt) {
    const int cur = tt & 1;
    // prefetch next double-tile into the other buffer (its old contents were
    // last read at iter tt-1; the end-of-(tt-1) barrier proves all waves done)
    if (tt + 1 < NT2) DSTAGE(cur ^ 1, (tt + 1) * 128);

    const char* K_ = (const char*)lK[cur];
    const char* VT_ = (const char*)lVT[cur];

    // swapped QK^T, rebased: sacc = S - mrow via MFMA C-init = -mrow.
    f32x4 nm4 = {nm, nm, nm, nm};
    f32x4 sacc[2][4];
    __builtin_amdgcn_s_setprio(1);
#pragma unroll
    for (int s64 = 0; s64 < 2; ++s64)
#pragma unroll
      for (int ct = 0; ct < 4; ++ct) {
        f32x4 z = nm4;
#pragma unroll
        for (int kk = 0; kk < 2; ++kk) {
          bf16x8 kf = *reinterpret_cast<const bf16x8*>(
              K_ + (((s64 * 64 + ct * 16 + l15) * 128 + kk * 64 + lhi * 16) ^ swzK));
          z = __builtin_amdgcn_mfma_f32_16x16x32_bf16(kf, qf[kk], z, 0, 0, 0);
        }
        sacc[s64][ct] = z;
      }
    __builtin_amdgcn_s_setprio(0);

    // per-lane max of 32 rebased scores (max3-friendly triples)
    float m0a = fmaxf(fmaxf(sacc[0][0][0], sacc[0][0][1]), fmaxf(sacc[0][0][2], sacc[0][0][3]));
    float m0b = fmaxf(fmaxf(sacc[0][1][0], sacc[0][1][1]), fmaxf(sacc[0][1][2], sacc[0][1][3]));
    float m0c = fmaxf(fmaxf(sacc[0][2][0], sacc[0][2][1]), fmaxf(sacc[0][2][2], sacc[0][2][3]));
    float m0d = fmaxf(fmaxf(sacc[0][3][0], sacc[0][3][1]), fmaxf(sacc[0][3][2], sacc[0][3][3]));
    float m1a = fmaxf(fmaxf(sacc[1][0][0], sacc[1][0][1]), fmaxf(sacc[1][0][2], sacc[1][0][3]));
    float m1b = fmaxf(fmaxf(sacc[1][1][0], sacc[1][1][1]), fmaxf(sacc[1][1][2], sacc[1][1][3]));
    float m1c = fmaxf(fmaxf(sacc[1][2][0], sacc[1][2][1]), fmaxf(sacc[1][2][2], sacc[1][2][3]));
    float m1d = fmaxf(fmaxf(sacc[1][3][0], sacc[1][3][1]), fmaxf(sacc[1][3][2], sacc[1][3][3]));
    float mt = fmaxf(fmaxf(fmaxf(m0a, m0b), fmaxf(m0c, m0d)),
                     fmaxf(fmaxf(m1a, m1b), fmaxf(m1c, m1d)));

    // defer-max: rescale only when some row's max grew past threshold.
    // Stale m keeps P <= 2^8 = 256 — fine in f32 accum / bf16 P.
    if (__any(mt > 8.0f)) {
      float mtr = fmaxf(mt, __shfl_xor(mt, 16));
      mtr = fmaxf(mtr, __shfl_xor(mtr, 32)); // row max (lanes sharing l15)
      float mte = fmaxf(mtr, 0.f);           // == old max(mrow, abs-max) semantics
      float corr = fexp2(-mte);
      nm -= mte;
#pragma unroll
      for (int jj = 0; jj < 4; ++jj) {
        float cO = __shfl(corr, lhi * 4 + jj); // corr of q-row lhi*4+jj
        lsum[jj] *= cO;
#pragma unroll
        for (int dt = 0; dt < 4; ++dt) xacc[dt][jj] *= cO;
      }
#pragma unroll
      for (int s64 = 0; s64 < 2; ++s64)
#pragma unroll
        for (int ct = 0; ct < 4; ++ct)
#pragma unroll
          for (int jj = 0; jj < 4; ++jj) sacc[s64][ct][jj] -= mte;
    }

    // P = exp2(sacc) straight to bf16 fragments; lsum + PV per subtile
    __builtin_amdgcn_s_setprio(1);
#pragma unroll
    for (int s64 = 0; s64 < 2; ++s64) {
      bf16x4 pa[4];
#pragma unroll
      for (int ct = 0; ct < 4; ++ct)
#pragma unroll
        for (int jj = 0; jj < 4; ++jj)
          pa[ct][jj] = (bf16_t)fexp2(sacc[s64][ct][jj]);
#pragma unroll
      for (int ct = 0; ct < 4; ++ct) lsum = mfma16(pa[ct], ones4, lsum);
#pragma unroll
      for (int dt = 0; dt < 4; ++dt) {
#pragma unroll
        for (int sel = 0; sel < 2; ++sel) {
          bf16x8 vb2 = *reinterpret_cast<const bf16x8*>(
              VT_ + (((dt * 16 + l15) * 256 + s64 * 128 + lhi * 32 + sel * 16) ^ swzK));
          bf16x4 vlo = __builtin_shufflevector(vb2, vb2, 0, 1, 2, 3);
          bf16x4 vhi = __builtin_shufflevector(vb2, vb2, 4, 5, 6, 7);
          xacc[dt] = mfma16(pa[2 * sel + 0], vlo, xacc[dt]);
          xacc[dt] = mfma16(pa[2 * sel + 1], vhi, xacc[dt]);
        }
      }
    }
    __builtin_amdgcn_s_setprio(0);

    // single drain+barrier per double-tile: prefetch had the whole compute
    // phase to land; next iteration overwrites the buffer everyone just read.
    asm volatile("s_waitcnt vmcnt(0)" ::: "memory");
    __builtin_amdgcn_s_barrier();
    __builtin_amdgcn_sched_barrier(0);
  }
#undef DSTAGE

  // lsum[jj] is already the row sum for output row lhi*4+jj — no shuffles.
  float iO[4];
#pragma unroll
  for (int jj = 0; jj < 4; ++jj) iO[jj] = 1.0f / lsum[jj];

  unsigned short* xp = X + base + (size_t)(q0 + wv * 16) * Dc + hoff;
#pragma unroll
  for (int dt = 0; dt < 4; ++dt)
#pragma unroll
    for (int jj = 0; jj < 4; ++jj) {
      int r = lhi * 4 + jj;
      xp[(size_t)r * Dc + dt * 16 + l15] = f2bf(xacc[dt][jj] * iO[jj]);
    }
}

// ---------------- launch ----------------
extern "C" void kernel_launch(void* const* d_in, const int* in_sizes, int n_in,
                              void* d_out, int out_size, void* d_ws, size_t ws_size,
                              hipStream_t stream) {
  const float* query = (const float*)d_in[0];
  const float* key   = (const float*)d_in[1];
  const float* value = (const float*)d_in[2];
  const float* Wq = (const float*)d_in[3];
  const float* bq = (const float*)d_in[4];
  const float* Wk = (const float*)d_in[5];
  const float* bk = (const float*)d_in[6];
  const float* Wv = (const float*)d_in[7];
  const float* bv = (const float*)d_in[8];
  const float* Wo = (const float*)d_in[9];
  const float* bo = (const float*)d_in[10];

  const size_t NBS = (size_t)Mrows * Dc; // 8388608
  const size_t NW  = (size_t)Dc * Dc;    // 1048576
  unsigned short* bQin = (unsigned short*)d_ws;
  unsigned short* bKin = bQin + NBS;
  unsigned short* bVin = bKin + NBS;
  unsigned short* bWq  = bVin + NBS;
  unsigned short* bWk  = bWq + NW;
  unsigned short* bWv  = bWk + NW;
  unsigned short* bWo  = bWv + NW;
  unsigned short* Qp   = bWo + NW;
  unsigned short* Kp   = Qp + NBS;
  unsigned short* Vtp  = Kp + NBS; // V projection, TRANSPOSED + field-swapped
  unsigned short* Xp   = Vtp + NBS;

  // inputs: 3 contiguous segments (bQin,bKin,bVin); lg = log2(NBS/4) = 21
  cvt_bf16_seg_kernel<<<(int)(3 * NBS / 1024), 256, 0, stream>>>(
      query, key, value, value, bQin, 21);
  // weights: 4 contiguous segments (bWq..bWo); lg = log2(NW/4) = 18
  cvt_bf16_seg_kernel<<<(int)(4 * NW / 1024), 256, 0, stream>>>(
      Wq, Wk, Wv, Wo, bWq, 18);

  // fused Q/K/V projections: z selects; Q prescale folds 1/sqrt(DK) AND
  // log2(e) (attn softmax runs in exp2 domain)
  gemm_dbuf_kernel<true><<<dim3(Dc / 128, Mrows / 128, 3), 256, 0, stream>>>(
      bQin, bKin, bVin, bWq, bWk, bWv, bq, bk, bv, Qp, Kp, Vtp,
      Mrows, Dc, Dc, 0.125f * 1.44269504088896340736f);

  attn_kernel<<<dim3(Sc / 128, Hc, Bc), 512, 0, stream>>>(Qp, Kp, Vtp, Xp);

  gemm_dbuf_kernel<false><<<dim3(Dc / 128, Mrows / 128, 1), 256, 0, stream>>>(
      Xp, nullptr, nullptr, bWo, nullptr, nullptr, bo, nullptr, nullptr,
      d_out, nullptr, nullptr, Mrows, Dc, Dc, 1.0f);
}

// Round 9
// 226.145 us; speedup vs baseline: 1.6698x; 1.0117x over previous
//
#include <hip/hip_runtime.h>
#include <stdint.h>

#define DEV static __device__ __forceinline__

typedef __bf16 bf16_t;
typedef bf16_t bf16x8 __attribute__((ext_vector_type(8)));
typedef bf16_t bf16x4 __attribute__((ext_vector_type(4)));
typedef float f32x4 __attribute__((ext_vector_type(4)));

static constexpr int Bc = 4, Sc = 2048, Dc = 1024, Hc = 16, DKc = 64;
static constexpr int Mrows = Bc * Sc; // 8192

DEV unsigned short f2bf(float f) {
  unsigned int u = __float_as_uint(f);
  u += 0x7fffu + ((u >> 16) & 1u);
  return (unsigned short)(u >> 16);
}

DEV float fexp2(float x) {
#if __has_builtin(__builtin_amdgcn_exp2f)
  return __builtin_amdgcn_exp2f(x); // single v_exp_f32
#else
  return exp2f(x);
#endif
}

// 16x16x16 bf16 MFMA (K=16): A-frag k-granularity = lhi*4 -- matches the
// swapped-QK^T D-layout exactly, so P feeds PV straight from registers.
#if __has_builtin(__builtin_amdgcn_mfma_f32_16x16x16_bf16)
DEV f32x4 mfma16(bf16x4 a, bf16x4 b, f32x4 c) {
  return __builtin_amdgcn_mfma_f32_16x16x16_bf16(a, b, c, 0, 0, 0);
}
#elif __has_builtin(__builtin_amdgcn_mfma_f32_16x16x16bf16_1k)
typedef short s16x4 __attribute__((ext_vector_type(4)));
DEV f32x4 mfma16(bf16x4 a, bf16x4 b, f32x4 c) {
  union U { bf16x4 h; s16x4 s; };
  U ua, ub; ua.h = a; ub.h = b;
  return __builtin_amdgcn_mfma_f32_16x16x16bf16_1k(ua.s, ub.s, c, 0, 0, 0);
}
#else
DEV f32x4 mfma16(bf16x4 a, bf16x4 b, f32x4 c) {
  asm("v_mfma_f32_16x16x16_bf16 %0, %1, %2, %0" : "+v"(c) : "v"(a), "v"(b));
  return c;
}
#endif

DEV void gload_lds16(const void* g, void* l) {
  __builtin_amdgcn_global_load_lds(
      (const __attribute__((address_space(1))) void*)g,
      (__attribute__((address_space(3))) void*)l, 16, 0, 0);
}

// 8 fp32 -> bf16x8 (RTNE; compiler emits v_cvt_pk_bf16_f32 pairs)
DEV bf16x8 cvt8(float4 a, float4 b) {
  bf16x8 r;
  r[0] = (bf16_t)a.x; r[1] = (bf16_t)a.y; r[2] = (bf16_t)a.z; r[3] = (bf16_t)a.w;
  r[4] = (bf16_t)b.x; r[5] = (bf16_t)b.y; r[6] = (bf16_t)b.z; r[7] = (bf16_t)b.w;
  return r;
}

// ---------------- fp32 -> bf16 conversion (segmented: up to 4 tensors) ------
// Now only used for the 4 weight matrices (input cvt is fused into the QKV
// GEMM's A-staging).
__global__ void __launch_bounds__(256) cvt_bf16_seg_kernel(
    const float* __restrict__ s0, const float* __restrict__ s1,
    const float* __restrict__ s2, const float* __restrict__ s3,
    unsigned short* __restrict__ out, int lg) {
  int i = blockIdx.x * blockDim.x + threadIdx.x;
  int seg = i >> lg, j = i & ((1 << lg) - 1);
  const float* src = seg == 0 ? s0 : seg == 1 ? s1 : seg == 2 ? s2 : s3;
  float4 v = reinterpret_cast<const float4*>(src)[j];
  ushort4 o;
  o.x = f2bf(v.x); o.y = f2bf(v.y); o.z = f2bf(v.z); o.w = f2bf(v.w);
  reinterpret_cast<ushort4*>(out)[i] = o;
}

// ---------------- GEMM: C[m][n] = (sum_k A[m][k]*W[n][k] + bias[n]) * scale ----
// W: [N][K] bf16 row-major (i.e. X @ W^T). 128x128 tile, BK=32, 256 threads
// (4 waves, 2x2), 16 16x16x32 MFMA per wave per K-step. 2-buffer pipeline
// (R6==R7 within noise): stage(next) -> MFMA(cur) -> [A-write] -> drain+barrier.
// QKV=true: A is FP32 (query/key/value read directly -- the input-cvt kernel
//   is fused here). A staged via reg: 4x global_load_dwordx4 issued BEFORE
//   the MFMA block (HBM latency hides under it), RTNE-cvt to bf16 and
//   2x ds_write_b128 AFTER (wave-contiguous 1KB -> conflict-free). W stays
//   on global_load_lds. blockIdx.z selects {Q,K,V}; V (z=2) stored
//   TRANSPOSED+kv-field-swapped (bits [5:4]<->[3:2] of s&63).
// QKV=false: A is bf16 (Xp), both operands via global_load_lds; f32 out.
// BK=32 row stride = 64 B -> 4-slot XOR swizzle for conflict-free b128 frag
// reads: SOURCE col slot ^ (row&3) (LDS dest linear), read byte ^ ((l15&3)<<4).
// XCD swizzle: per-z-slice hw id -> (hw%8)*chunk + hw/8.
template <bool QKV>
__global__ void __launch_bounds__(256) gemm_dbuf_kernel(
    const void* __restrict__ A0v, const void* __restrict__ A1v,
    const void* __restrict__ A2v,
    const unsigned short* __restrict__ W0, const unsigned short* __restrict__ W1,
    const unsigned short* __restrict__ W2,
    const float* __restrict__ b0, const float* __restrict__ b1,
    const float* __restrict__ b2,
    void* __restrict__ C0, void* __restrict__ C1, void* __restrict__ C2,
    int M, int N, int K, float scale0) {
  __shared__ unsigned short lA[2][128 * 32];
  __shared__ unsigned short lB[2][128 * 32];
  const int t = threadIdx.x;
  const int wv = t >> 6, ln = t & 63;
  const int l15 = ln & 15, lhi = ln >> 4;

  const void* Av; const unsigned short* W;
  const float* bias; void* Cout; float scale; int mode;
  if (QKV) {
    const int z = blockIdx.z;
    Av = z == 0 ? A0v : z == 1 ? A1v : A2v;
    W = z == 0 ? W0 : z == 1 ? W1 : W2;
    bias = z == 0 ? b0 : z == 1 ? b1 : b2;
    Cout = z == 0 ? C0 : z == 1 ? C1 : C2;
    scale = z == 0 ? scale0 : 1.0f;
    mode = z == 2 ? 2 : 1;
  } else {
    Av = A0v; W = W0; bias = b0; Cout = C0; scale = scale0; mode = 0;
  }

  // XCD-chunked remap (bijective; per-slice grid = 512, multiple of 8)
  const int nwg = gridDim.x * gridDim.y;
  const int hw = blockIdx.y * gridDim.x + blockIdx.x;
  const int chunk = nwg >> 3;
  const int swzid = (hw & 7) * chunk + (hw >> 3);
  const int m0 = (swzid / gridDim.x) * 128, n0 = (swzid % gridDim.x) * 128;
  const int wr = wv >> 1, wc = wv & 1;
  const int swzR = (l15 & 3) << 4; // frag-read byte XOR (row&3 == l15&3)

  // staging: thread t covers rows (t>>2) and (t>>2)+64, 8 elems each, source
  // col pre-swizzled (both rows share row&3, so one swizzled col serves both)
  const int rowA = t >> 2;
  const int colS = ((t & 3) ^ (rowA & 3)) * 8;
  const unsigned short* wS = W + (size_t)(n0 + rowA) * K + colS;
  const size_t rstep = (size_t)64 * K;
  const int d0 = t * 16, d1 = 4096 + t * 16;
  // A source (type depends on QKV)
  const float* aF = QKV ? (const float*)Av + (size_t)(m0 + rowA) * K + colS : nullptr;
  const unsigned short* aB =
      QKV ? nullptr : (const unsigned short*)Av + (size_t)(m0 + rowA) * K + colS;

  f32x4 acc[4][4] = {};

#define WSTAGE(bi, k0_)                                        \
  do {                                                         \
    gload_lds16(wS + (k0_), (char*)lB[bi] + d0);               \
    gload_lds16(wS + rstep + (k0_), (char*)lB[bi] + d1);       \
  } while (0)
#define ABSTAGE(bi, k0_)                                       \
  do {                                                         \
    gload_lds16(aB + (k0_), (char*)lA[bi] + d0);               \
    gload_lds16(aB + rstep + (k0_), (char*)lA[bi] + d1);       \
  } while (0)

  // prologue: tile 0 fully staged
  WSTAGE(0, 0);
  if (QKV) {
    float4 a0 = *(const float4*)(aF);
    float4 a1 = *(const float4*)(aF + 4);
    float4 a2 = *(const float4*)(aF + rstep);
    float4 a3 = *(const float4*)(aF + rstep + 4);
    *reinterpret_cast<bf16x8*>((char*)lA[0] + d0) = cvt8(a0, a1);
    *reinterpret_cast<bf16x8*>((char*)lA[0] + d1) = cvt8(a2, a3);
  } else {
    ABSTAGE(0, 0);
  }
  asm volatile("s_waitcnt vmcnt(0) lgkmcnt(0)" ::: "memory");
  __builtin_amdgcn_s_barrier();
  __builtin_amdgcn_sched_barrier(0);

  const int NK = K >> 5; // 32
  for (int tk = 0; tk < NK; ++tk) {
    const int cur = tk & 1, nxt = cur ^ 1;
    float4 a0, a1, a2, a3;
    const bool pre = (tk + 1 < NK);
    if (pre) {
      WSTAGE(nxt, (tk + 1) * 32);
      if (QKV) { // issue A fp32 loads now; consumed after the MFMA block
        const float* p = aF + (tk + 1) * 32;
        a0 = *(const float4*)(p);
        a1 = *(const float4*)(p + 4);
        a2 = *(const float4*)(p + rstep);
        a3 = *(const float4*)(p + rstep + 4);
      } else {
        ABSTAGE(nxt, (tk + 1) * 32);
      }
    }

    bf16x8 af[4], bfr[4];
#pragma unroll
    for (int i = 0; i < 4; ++i)
      af[i] = *reinterpret_cast<const bf16x8*>(
          (char*)lA[cur] + (((wr * 64 + i * 16 + l15) * 64 + lhi * 16) ^ swzR));
#pragma unroll
    for (int j = 0; j < 4; ++j)
      bfr[j] = *reinterpret_cast<const bf16x8*>(
          (char*)lB[cur] + (((wc * 64 + j * 16 + l15) * 64 + lhi * 16) ^ swzR));
#pragma unroll
    for (int i = 0; i < 4; ++i)
#pragma unroll
      for (int j = 0; j < 4; ++j)
        acc[i][j] = __builtin_amdgcn_mfma_f32_16x16x32_bf16(af[i], bfr[j], acc[i][j], 0, 0, 0);

    if (QKV && pre) { // cvt + LDS write (loads had the whole MFMA to land)
      *reinterpret_cast<bf16x8*>((char*)lA[nxt] + d0) = cvt8(a0, a1);
      *reinterpret_cast<bf16x8*>((char*)lA[nxt] + d1) = cvt8(a2, a3);
    }

    // drain (W gload_lds + A writes) and publish buffer nxt; the barrier also
    // proves all waves finished reading cur, so iter tk+1 may overwrite it.
    asm volatile("s_waitcnt vmcnt(0) lgkmcnt(0)" ::: "memory");
    __builtin_amdgcn_s_barrier();
    __builtin_amdgcn_sched_barrier(0);
  }
#undef WSTAGE
#undef ABSTAGE

#pragma unroll
  for (int i = 0; i < 4; ++i)
#pragma unroll
    for (int j = 0; j < 4; ++j) {
      int n = n0 + wc * 64 + j * 16 + l15;
      float bv = bias[n];
      if (QKV && mode == 2) {
        int mb = m0 + wr * 64 + i * 16 + lhi * 4; // 4 consecutive m = consecutive s
        int sl = mb & (Sc - 1);
        // field-swap bits [5:4]<->[3:2] (low 2 bits untouched -> ushort4 ok)
        int pl = (sl & ~60) | ((sl & 48) >> 2) | ((sl & 12) << 2);
        ushort4 ov;
        ov.x = f2bf((acc[i][j][0] + bv) * scale);
        ov.y = f2bf((acc[i][j][1] + bv) * scale);
        ov.z = f2bf((acc[i][j][2] + bv) * scale);
        ov.w = f2bf((acc[i][j][3] + bv) * scale);
        *reinterpret_cast<ushort4*>((unsigned short*)Cout +
            ((size_t)(mb >> 11) * Dc + n) * Sc + pl) = ov;
      } else {
#pragma unroll
        for (int jj = 0; jj < 4; ++jj) {
          int m = m0 + wr * 64 + i * 16 + lhi * 4 + jj;
          float v = (acc[i][j][jj] + bv) * scale;
          if (QKV)
            ((unsigned short*)Cout)[(size_t)m * N + n] = f2bf(v);
          else
            ((float*)Cout)[(size_t)m * N + n] = v;
        }
      }
    }
}

// ---------------- Flash attention ----------------
// (unchanged from R8 -- interior-balanced at 112 us; frozen)
__global__ void __launch_bounds__(512, 4) attn_kernel(
    const unsigned short* __restrict__ Q, const unsigned short* __restrict__ Kk,
    const unsigned short* __restrict__ Vt, unsigned short* __restrict__ X) {
  __shared__ unsigned short lK[2][128 * 64];  // [kv][dk], XOR-swizzled
  __shared__ unsigned short lVT[2][64 * 128]; // [dk][swapped-kv], XOR-swizzled
  const int t = threadIdx.x;
  const int wv = t >> 6, ln = t & 63;
  const int l15 = ln & 15, lhi = ln >> 4;
  const int q0 = blockIdx.x * 128;
  const int h = blockIdx.y, b = blockIdx.z;
  const size_t base = (size_t)b * Sc * Dc;
  const int hoff = h * DKc;

  bf16x8 qf[2];
  {
    const unsigned short* qp = Q + base + (size_t)(q0 + wv * 16 + l15) * Dc + hoff + lhi * 8;
    qf[0] = *reinterpret_cast<const bf16x8*>(qp);
    qf[1] = *reinterpret_cast<const bf16x8*>(qp + 32);
  }

  const int kvr = t >> 3;
  const int kcol = ((t & 7) * 8) ^ ((kvr & 7) << 3);
  const unsigned short* kS = Kk + base + (size_t)kvr * Dc + hoff + kcol;
  const int vdk = t >> 4;
  const int vkv = ((t & 15) * 8) ^ ((vdk & 7) << 3);
  const unsigned short* vS = Vt + ((size_t)b * Dc + hoff + vdk) * Sc + vkv;

  float nm = 0.f;       // nm = -mrow for q-row l15 (x4 replicated)
  f32x4 xacc[4] = {};   // out rows lhi*4+jj, cols dt*16+l15
  f32x4 lsum = {};      // row sums for rows lhi*4+jj (ones-MFMA)
  const int swzK = (l15 & 7) << 4;

  bf16x4 ones4;
#pragma unroll
  for (int i = 0; i < 4; ++i) ones4[i] = (bf16_t)1.0f;

#define DSTAGE(bi, kv0_)                                                        \
  do {                                                                          \
    gload_lds16(kS + (size_t)(kv0_)*Dc, (char*)lK[bi] + t * 16);                \
    gload_lds16(kS + (size_t)((kv0_) + 64) * Dc, (char*)lK[bi] + 8192 + t * 16);\
    gload_lds16(vS + (kv0_), (char*)lVT[bi] + t * 16);                          \
    gload_lds16(vS + (size_t)32 * Sc + (kv0_), (char*)lVT[bi] + 8192 + t * 16); \
  } while (0)

  DSTAGE(0, 0);
  asm volatile("s_waitcnt vmcnt(0)" ::: "memory");
  __builtin_amdgcn_s_barrier();
  __builtin_amdgcn_sched_barrier(0);

  const int NT2 = Sc / 128; // 16
  for (int tt = 0; tt < NT2; ++tt) {
    const int cur = tt & 1;
    if (tt + 1 < NT2) DSTAGE(cur ^ 1, (tt + 1) * 128);

    const char* K_ = (const char*)lK[cur];
    const char* VT_ = (const char*)lVT[cur];

    // swapped QK^T, rebased: sacc = S - mrow via MFMA C-init = -mrow.
    f32x4 nm4 = {nm, nm, nm, nm};
    f32x4 sacc[2][4];
    __builtin_amdgcn_s_setprio(1);
#pragma unroll
    for (int s64 = 0; s64 < 2; ++s64)
#pragma unroll
      for (int ct = 0; ct < 4; ++ct) {
        f32x4 z = nm4;
#pragma unroll
        for (int kk = 0; kk < 2; ++kk) {
          bf16x8 kf = *reinterpret_cast<const bf16x8*>(
              K_ + (((s64 * 64 + ct * 16 + l15) * 128 + kk * 64 + lhi * 16) ^ swzK));
          z = __builtin_amdgcn_mfma_f32_16x16x32_bf16(kf, qf[kk], z, 0, 0, 0);
        }
        sacc[s64][ct] = z;
      }
    __builtin_amdgcn_s_setprio(0);

    float m0a = fmaxf(fmaxf(sacc[0][0][0], sacc[0][0][1]), fmaxf(sacc[0][0][2], sacc[0][0][3]));
    float m0b = fmaxf(fmaxf(sacc[0][1][0], sacc[0][1][1]), fmaxf(sacc[0][1][2], sacc[0][1][3]));
    float m0c = fmaxf(fmaxf(sacc[0][2][0], sacc[0][2][1]), fmaxf(sacc[0][2][2], sacc[0][2][3]));
    float m0d = fmaxf(fmaxf(sacc[0][3][0], sacc[0][3][1]), fmaxf(sacc[0][3][2], sacc[0][3][3]));
    float m1a = fmaxf(fmaxf(sacc[1][0][0], sacc[1][0][1]), fmaxf(sacc[1][0][2], sacc[1][0][3]));
    float m1b = fmaxf(fmaxf(sacc[1][1][0], sacc[1][1][1]), fmaxf(sacc[1][1][2], sacc[1][1][3]));
    float m1c = fmaxf(fmaxf(sacc[1][2][0], sacc[1][2][1]), fmaxf(sacc[1][2][2], sacc[1][2][3]));
    float m1d = fmaxf(fmaxf(sacc[1][3][0], sacc[1][3][1]), fmaxf(sacc[1][3][2], sacc[1][3][3]));
    float mt = fmaxf(fmaxf(fmaxf(m0a, m0b), fmaxf(m0c, m0d)),
                     fmaxf(fmaxf(m1a, m1b), fmaxf(m1c, m1d)));

    if (__any(mt > 8.0f)) {
      float mtr = fmaxf(mt, __shfl_xor(mt, 16));
      mtr = fmaxf(mtr, __shfl_xor(mtr, 32));
      float mte = fmaxf(mtr, 0.f);
      float corr = fexp2(-mte);
      nm -= mte;
#pragma unroll
      for (int jj = 0; jj < 4; ++jj) {
        float cO = __shfl(corr, lhi * 4 + jj);
        lsum[jj] *= cO;
#pragma unroll
        for (int dt = 0; dt < 4; ++dt) xacc[dt][jj] *= cO;
      }
#pragma unroll
      for (int s64 = 0; s64 < 2; ++s64)
#pragma unroll
        for (int ct = 0; ct < 4; ++ct)
#pragma unroll
          for (int jj = 0; jj < 4; ++jj) sacc[s64][ct][jj] -= mte;
    }

    __builtin_amdgcn_s_setprio(1);
#pragma unroll
    for (int s64 = 0; s64 < 2; ++s64) {
      bf16x4 pa[4];
#pragma unroll
      for (int ct = 0; ct < 4; ++ct)
#pragma unroll
        for (int jj = 0; jj < 4; ++jj)
          pa[ct][jj] = (bf16_t)fexp2(sacc[s64][ct][jj]);
#pragma unroll
      for (int ct = 0; ct < 4; ++ct) lsum = mfma16(pa[ct], ones4, lsum);
#pragma unroll
      for (int dt = 0; dt < 4; ++dt) {
#pragma unroll
        for (int sel = 0; sel < 2; ++sel) {
          bf16x8 vb2 = *reinterpret_cast<const bf16x8*>(
              VT_ + (((dt * 16 + l15) * 256 + s64 * 128 + lhi * 32 + sel * 16) ^ swzK));
          bf16x4 vlo = __builtin_shufflevector(vb2, vb2, 0, 1, 2, 3);
          bf16x4 vhi = __builtin_shufflevector(vb2, vb2, 4, 5, 6, 7);
          xacc[dt] = mfma16(pa[2 * sel + 0], vlo, xacc[dt]);
          xacc[dt] = mfma16(pa[2 * sel + 1], vhi, xacc[dt]);
        }
      }
    }
    __builtin_amdgcn_s_setprio(0);

    asm volatile("s_waitcnt vmcnt(0)" ::: "memory");
    __builtin_amdgcn_s_barrier();
    __builtin_amdgcn_sched_barrier(0);
  }
#undef DSTAGE

  float iO[4];
#pragma unroll
  for (int jj = 0; jj < 4; ++jj) iO[jj] = 1.0f / lsum[jj];

  unsigned short* xp = X + base + (size_t)(q0 + wv * 16) * Dc + hoff;
#pragma unroll
  for (int dt = 0; dt < 4; ++dt)
#pragma unroll
    for (int jj = 0; jj < 4; ++jj) {
      int r = lhi * 4 + jj;
      xp[(size_t)r * Dc + dt * 16 + l15] = f2bf(xacc[dt][jj] * iO[jj]);
    }
}

// ---------------- launch ----------------
extern "C" void kernel_launch(void* const* d_in, const int* in_sizes, int n_in,
                              void* d_out, int out_size, void* d_ws, size_t ws_size,
                              hipStream_t stream) {
  const float* query = (const float*)d_in[0];
  const float* key   = (const float*)d_in[1];
  const float* value = (const float*)d_in[2];
  const float* Wq = (const float*)d_in[3];
  const float* bq = (const float*)d_in[4];
  const float* Wk = (const float*)d_in[5];
  const float* bk = (const float*)d_in[6];
  const float* Wv = (const float*)d_in[7];
  const float* bv = (const float*)d_in[8];
  const float* Wo = (const float*)d_in[9];
  const float* bo = (const float*)d_in[10];

  const size_t NBS = (size_t)Mrows * Dc; // 8388608
  const size_t NW  = (size_t)Dc * Dc;    // 1048576
  unsigned short* bWq  = (unsigned short*)d_ws;
  unsigned short* bWk  = bWq + NW;
  unsigned short* bWv  = bWk + NW;
  unsigned short* bWo  = bWv + NW;
  unsigned short* Qp   = bWo + NW;
  unsigned short* Kp   = Qp + NBS;
  unsigned short* Vtp  = Kp + NBS; // V projection, TRANSPOSED + field-swapped
  unsigned short* Xp   = Vtp + NBS;

  // weights: 4 contiguous segments (bWq..bWo); lg = log2(NW/4) = 18
  // (input fp32->bf16 cvt is fused into the QKV GEMM's A-staging)
  cvt_bf16_seg_kernel<<<(int)(4 * NW / 1024), 256, 0, stream>>>(
      Wq, Wk, Wv, Wo, bWq, 18);

  // fused Q/K/V projections, fp32-A: z selects; Q prescale folds 1/sqrt(DK)
  // AND log2(e) (attn softmax runs in exp2 domain)
  gemm_dbuf_kernel<true><<<dim3(Dc / 128, Mrows / 128, 3), 256, 0, stream>>>(
      query, key, value, bWq, bWk, bWv, bq, bk, bv, Qp, Kp, Vtp,
      Mrows, Dc, Dc, 0.125f * 1.44269504088896340736f);

  attn_kernel<<<dim3(Sc / 128, Hc, Bc), 512, 0, stream>>>(Qp, Kp, Vtp, Xp);

  gemm_dbuf_kernel<false><<<dim3(Dc / 128, Mrows / 128, 1), 256, 0, stream>>>(
      Xp, nullptr, nullptr, bWo, nullptr, nullptr, bo, nullptr, nullptr,
      d_out, nullptr, nullptr, Mrows, Dc, Dc, 1.0f);
}

// Round 10
// 220.132 us; speedup vs baseline: 1.7154x; 1.0273x over previous
//
#include <hip/hip_runtime.h>
#include <stdint.h>

#define DEV static __device__ __forceinline__

typedef __bf16 bf16_t;
typedef bf16_t bf16x8 __attribute__((ext_vector_type(8)));
typedef bf16_t bf16x4 __attribute__((ext_vector_type(4)));
typedef float f32x4 __attribute__((ext_vector_type(4)));

static constexpr int Bc = 4, Sc = 2048, Dc = 1024, Hc = 16, DKc = 64;
static constexpr int Mrows = Bc * Sc; // 8192

DEV unsigned short f2bf(float f) {
  unsigned int u = __float_as_uint(f);
  u += 0x7fffu + ((u >> 16) & 1u);
  return (unsigned short)(u >> 16);
}

DEV float fexp2(float x) {
#if __has_builtin(__builtin_amdgcn_exp2f)
  return __builtin_amdgcn_exp2f(x); // single v_exp_f32
#else
  return exp2f(x);
#endif
}

// 16x16x16 bf16 MFMA (K=16): A-frag k-granularity = lhi*4 -- matches the
// swapped-QK^T D-layout exactly, so P feeds PV straight from registers.
#if __has_builtin(__builtin_amdgcn_mfma_f32_16x16x16_bf16)
DEV f32x4 mfma16(bf16x4 a, bf16x4 b, f32x4 c) {
  return __builtin_amdgcn_mfma_f32_16x16x16_bf16(a, b, c, 0, 0, 0);
}
#elif __has_builtin(__builtin_amdgcn_mfma_f32_16x16x16bf16_1k)
typedef short s16x4 __attribute__((ext_vector_type(4)));
DEV f32x4 mfma16(bf16x4 a, bf16x4 b, f32x4 c) {
  union U { bf16x4 h; s16x4 s; };
  U ua, ub; ua.h = a; ub.h = b;
  return __builtin_amdgcn_mfma_f32_16x16x16bf16_1k(ua.s, ub.s, c, 0, 0, 0);
}
#else
DEV f32x4 mfma16(bf16x4 a, bf16x4 b, f32x4 c) {
  asm("v_mfma_f32_16x16x16_bf16 %0, %1, %2, %0" : "+v"(c) : "v"(a), "v"(b));
  return c;
}
#endif

DEV void gload_lds16(const void* g, void* l) {
  __builtin_amdgcn_global_load_lds(
      (const __attribute__((address_space(1))) void*)g,
      (__attribute__((address_space(3))) void*)l, 16, 0, 0);
}

// 8 fp32 -> bf16x8 (RTNE; compiler emits v_cvt_pk_bf16_f32 pairs)
DEV bf16x8 cvt8(float4 a, float4 b) {
  bf16x8 r;
  r[0] = (bf16_t)a.x; r[1] = (bf16_t)a.y; r[2] = (bf16_t)a.z; r[3] = (bf16_t)a.w;
  r[4] = (bf16_t)b.x; r[5] = (bf16_t)b.y; r[6] = (bf16_t)b.z; r[7] = (bf16_t)b.w;
  return r;
}

// ---------------- fp32 -> bf16 conversion (weights only) --------------------
__global__ void __launch_bounds__(256) cvt_bf16_seg_kernel(
    const float* __restrict__ s0, const float* __restrict__ s1,
    const float* __restrict__ s2, const float* __restrict__ s3,
    unsigned short* __restrict__ out, int lg) {
  int i = blockIdx.x * blockDim.x + threadIdx.x;
  int seg = i >> lg, j = i & ((1 << lg) - 1);
  const float* src = seg == 0 ? s0 : seg == 1 ? s1 : seg == 2 ? s2 : s3;
  float4 v = reinterpret_cast<const float4*>(src)[j];
  ushort4 o;
  o.x = f2bf(v.x); o.y = f2bf(v.y); o.z = f2bf(v.z); o.w = f2bf(v.w);
  reinterpret_cast<ushort4*>(out)[i] = o;
}

// ---------------- GEMM: C[m][n] = (sum_k A[m][k]*W[n][k] + bias[n]) * scale ----
// W: [N][K] bf16 row-major (i.e. X @ W^T). 128x128 tile, BK=32, 256 threads
// (4 waves, 2x2), 16 16x16x32 MFMA per wave per K-step. 3 LDS buffers.
//
// QKV=true (fp32-A, cvt fused): T14 DEPTH-2 REG-STAGING. R9's version loaded
//   and consumed A in the SAME iteration -> each K-step serially ate the full
//   HBM latency (MfmaUtil 13.7%). Now: iter tk issues W(tk+2) [gload_lds] and
//   A(tk+2) [4x dwordx4 -> regs]; MFMA(tk); THEN cvt+ds_write A(tk+1) (loaded
//   LAST iter -- one full iteration of latency cover; the compiler's implicit
//   vmcnt for those regs is <=6, so tk+2's 6 loads STAY IN FLIGHT); then
//   vmcnt(6)+lgkmcnt(0)+barrier. Never vmcnt(0) mid-loop (T4/m218).
//   Buffers tk, tk+1, tk+2 mod 3 are distinct; every overwrite targets a
//   buffer last read >=1 barrier ago.
// QKV=false (bf16-A, output proj): R7 counted scheme -- 4 gload_lds/iter,
//   top-of-loop vmcnt(4)+barrier, depth-2.
//
// BK=32 row stride = 64 B -> 4-slot XOR swizzle for conflict-free b128 frag
// reads: SOURCE col slot ^ (row&3) (LDS dest linear), read byte ^ ((l15&3)<<4).
// XCD swizzle: per-z-slice hw id -> (hw%8)*chunk + hw/8.
// QKV z=2 (V) stored TRANSPOSED+kv-field-swapped (bits [5:4]<->[3:2] of s&63).
template <bool QKV>
__global__ void __launch_bounds__(256) gemm_dbuf_kernel(
    const void* __restrict__ A0v, const void* __restrict__ A1v,
    const void* __restrict__ A2v,
    const unsigned short* __restrict__ W0, const unsigned short* __restrict__ W1,
    const unsigned short* __restrict__ W2,
    const float* __restrict__ b0, const float* __restrict__ b1,
    const float* __restrict__ b2,
    void* __restrict__ C0, void* __restrict__ C1, void* __restrict__ C2,
    int M, int N, int K, float scale0) {
  __shared__ unsigned short lA[3][128 * 32];
  __shared__ unsigned short lB[3][128 * 32];
  const int t = threadIdx.x;
  const int wv = t >> 6, ln = t & 63;
  const int l15 = ln & 15, lhi = ln >> 4;

  const void* Av; const unsigned short* W;
  const float* bias; void* Cout; float scale; int mode;
  if (QKV) {
    const int z = blockIdx.z;
    Av = z == 0 ? A0v : z == 1 ? A1v : A2v;
    W = z == 0 ? W0 : z == 1 ? W1 : W2;
    bias = z == 0 ? b0 : z == 1 ? b1 : b2;
    Cout = z == 0 ? C0 : z == 1 ? C1 : C2;
    scale = z == 0 ? scale0 : 1.0f;
    mode = z == 2 ? 2 : 1;
  } else {
    Av = A0v; W = W0; bias = b0; Cout = C0; scale = scale0; mode = 0;
  }

  // XCD-chunked remap (bijective; per-slice grid = 512, multiple of 8)
  const int nwg = gridDim.x * gridDim.y;
  const int hw = blockIdx.y * gridDim.x + blockIdx.x;
  const int chunk = nwg >> 3;
  const int swzid = (hw & 7) * chunk + (hw >> 3);
  const int m0 = (swzid / gridDim.x) * 128, n0 = (swzid % gridDim.x) * 128;
  const int wr = wv >> 1, wc = wv & 1;
  const int swzR = (l15 & 3) << 4; // frag-read byte XOR (row&3 == l15&3)

  // staging: thread t covers rows (t>>2) and (t>>2)+64, 8 elems each, source
  // col pre-swizzled (both rows share row&3, so one swizzled col serves both)
  const int rowA = t >> 2;
  const int colS = ((t & 3) ^ (rowA & 3)) * 8;
  const unsigned short* wS = W + (size_t)(n0 + rowA) * K + colS;
  const size_t rstep = (size_t)64 * K;
  const int d0 = t * 16, d1 = 4096 + t * 16;
  const float* aF = QKV ? (const float*)Av + (size_t)(m0 + rowA) * K + colS : nullptr;
  const unsigned short* aB =
      QKV ? nullptr : (const unsigned short*)Av + (size_t)(m0 + rowA) * K + colS;

  f32x4 acc[4][4] = {};
  const int NK = K >> 5; // 32

#define WST(bi, k0_)                                           \
  do {                                                         \
    gload_lds16(wS + (k0_), (char*)lB[bi] + d0);               \
    gload_lds16(wS + rstep + (k0_), (char*)lB[bi] + d1);       \
  } while (0)

#define MFMA_BLOCK(cur_)                                                        \
  do {                                                                          \
    bf16x8 af[4], bfr[4];                                                       \
    _Pragma("unroll") for (int i = 0; i < 4; ++i)                               \
      af[i] = *reinterpret_cast<const bf16x8*>(                                 \
          (char*)lA[cur_] + (((wr * 64 + i * 16 + l15) * 64 + lhi * 16) ^ swzR));\
    _Pragma("unroll") for (int j = 0; j < 4; ++j)                               \
      bfr[j] = *reinterpret_cast<const bf16x8*>(                                \
          (char*)lB[cur_] + (((wc * 64 + j * 16 + l15) * 64 + lhi * 16) ^ swzR));\
    _Pragma("unroll") for (int i = 0; i < 4; ++i)                               \
      _Pragma("unroll") for (int j = 0; j < 4; ++j)                             \
        acc[i][j] = __builtin_amdgcn_mfma_f32_16x16x32_bf16(af[i], bfr[j],      \
                                                            acc[i][j], 0, 0, 0);\
  } while (0)

  if (QKV) {
    float4 a0, a1, a2, a3;      // aC: A-tile for NEXT iteration's ds_write
    float4 n0_, n1_, n2_, n3_;  // aN: loads in flight for tile tk+2
#define ALD(k0_)                                               \
  do {                                                         \
    const float* p = aF + (k0_);                               \
    a0 = *(const float4*)(p);     a1 = *(const float4*)(p + 4);\
    a2 = *(const float4*)(p + rstep); a3 = *(const float4*)(p + rstep + 4);\
  } while (0)
#define ALDN(k0_)                                              \
  do {                                                         \
    const float* p = aF + (k0_);                               \
    n0_ = *(const float4*)(p);     n1_ = *(const float4*)(p + 4);\
    n2_ = *(const float4*)(p + rstep); n3_ = *(const float4*)(p + rstep + 4);\
  } while (0)
#define AWR(bi)                                                \
  do {                                                         \
    *reinterpret_cast<bf16x8*>((char*)lA[bi] + d0) = cvt8(a0, a1);\
    *reinterpret_cast<bf16x8*>((char*)lA[bi] + d1) = cvt8(a2, a3);\
  } while (0)
    // prologue: tile0 A+W staged; tile1 W + A-regs in flight
    WST(0, 0);
    ALD(0);
    AWR(0);            // implicit vmcnt wait for A(0) (also covers older W(0))
    WST(1, 32);
    ALD(32);           // aC = A(tile 1); 6 VMEM ops now in flight
    asm volatile("s_waitcnt vmcnt(6) lgkmcnt(0)" ::: "memory");
    __builtin_amdgcn_s_barrier();
    __builtin_amdgcn_sched_barrier(0);

    for (int tk = 0; tk < NK; ++tk) {
      const int cur = tk % 3;
      const bool hn = (tk + 1 < NK), hn2 = (tk + 2 < NK);
      if (hn2) {
        WST((tk + 2) % 3, (tk + 2) * 32);
        ALDN((tk + 2) * 32);
      }
      __builtin_amdgcn_sched_barrier(0); // keep load-issue above the MFMAs
      MFMA_BLOCK(cur);
      if (hn) AWR((tk + 1) % 3); // consumes aC (loaded LAST iter; implicit
                                 // vmcnt<=6 leaves tk+2's loads in flight)
      if (hn2) { a0 = n0_; a1 = n1_; a2 = n2_; a3 = n3_; }
      if (hn2)
        asm volatile("s_waitcnt vmcnt(6) lgkmcnt(0)" ::: "memory");
      else
        asm volatile("s_waitcnt vmcnt(0) lgkmcnt(0)" ::: "memory");
      __builtin_amdgcn_s_barrier(); // publishes lA[tk+1] + lB[tk+1]
      __builtin_amdgcn_sched_barrier(0);
    }
#undef ALD
#undef ALDN
#undef AWR
  } else {
    // bf16-A output projection: R7 counted scheme (4 gload_lds/iter, vmcnt(4))
#define AST(bi, k0_)                                           \
  do {                                                         \
    gload_lds16(aB + (k0_), (char*)lA[bi] + d0);               \
    gload_lds16(aB + rstep + (k0_), (char*)lA[bi] + d1);       \
  } while (0)
    AST(0, 0); WST(0, 0);
    AST(1, 32); WST(1, 32);
    for (int tk = 0; tk < NK; ++tk) {
      const int cur = tk % 3;
      if (tk == NK - 1)
        asm volatile("s_waitcnt vmcnt(0)" ::: "memory");
      else
        asm volatile("s_waitcnt vmcnt(4)" ::: "memory");
      __builtin_amdgcn_s_barrier();
      __builtin_amdgcn_sched_barrier(0);
      if (tk + 2 < NK) {
        AST((tk + 2) % 3, (tk + 2) * 32);
        WST((tk + 2) % 3, (tk + 2) * 32);
      }
      MFMA_BLOCK(cur);
    }
#undef AST
  }
#undef WST
#undef MFMA_BLOCK

#pragma unroll
  for (int i = 0; i < 4; ++i)
#pragma unroll
    for (int j = 0; j < 4; ++j) {
      int n = n0 + wc * 64 + j * 16 + l15;
      float bv = bias[n];
      if (QKV && mode == 2) {
        int mb = m0 + wr * 64 + i * 16 + lhi * 4; // 4 consecutive m = consecutive s
        int sl = mb & (Sc - 1);
        // field-swap bits [5:4]<->[3:2] (low 2 bits untouched -> ushort4 ok)
        int pl = (sl & ~60) | ((sl & 48) >> 2) | ((sl & 12) << 2);
        ushort4 ov;
        ov.x = f2bf((acc[i][j][0] + bv) * scale);
        ov.y = f2bf((acc[i][j][1] + bv) * scale);
        ov.z = f2bf((acc[i][j][2] + bv) * scale);
        ov.w = f2bf((acc[i][j][3] + bv) * scale);
        *reinterpret_cast<ushort4*>((unsigned short*)Cout +
            ((size_t)(mb >> 11) * Dc + n) * Sc + pl) = ov;
      } else {
#pragma unroll
        for (int jj = 0; jj < 4; ++jj) {
          int m = m0 + wr * 64 + i * 16 + lhi * 4 + jj;
          float v = (acc[i][j][jj] + bv) * scale;
          if (QKV)
            ((unsigned short*)Cout)[(size_t)m * N + n] = f2bf(v);
          else
            ((float*)Cout)[(size_t)m * N + n] = v;
        }
      }
    }
}

// ---------------- Flash attention ----------------
// (unchanged from R8 -- interior-balanced at 112 us; frozen)
__global__ void __launch_bounds__(512, 4) attn_kernel(
    const unsigned short* __restrict__ Q, const unsigned short* __restrict__ Kk,
    const unsigned short* __restrict__ Vt, unsigned short* __restrict__ X) {
  __shared__ unsigned short lK[2][128 * 64];  // [kv][dk], XOR-swizzled
  __shared__ unsigned short lVT[2][64 * 128]; // [dk][swapped-kv], XOR-swizzled
  const int t = threadIdx.x;
  const int wv = t >> 6, ln = t & 63;
  const int l15 = ln & 15, lhi = ln >> 4;
  const int q0 = blockIdx.x * 128;
  const int h = blockIdx.y, b = blockIdx.z;
  const size_t base = (size_t)b * Sc * Dc;
  const int hoff = h * DKc;

  bf16x8 qf[2];
  {
    const unsigned short* qp = Q + base + (size_t)(q0 + wv * 16 + l15) * Dc + hoff + lhi * 8;
    qf[0] = *reinterpret_cast<const bf16x8*>(qp);
    qf[1] = *reinterpret_cast<const bf16x8*>(qp + 32);
  }

  const int kvr = t >> 3;
  const int kcol = ((t & 7) * 8) ^ ((kvr & 7) << 3);
  const unsigned short* kS = Kk + base + (size_t)kvr * Dc + hoff + kcol;
  const int vdk = t >> 4;
  const int vkv = ((t & 15) * 8) ^ ((vdk & 7) << 3);
  const unsigned short* vS = Vt + ((size_t)b * Dc + hoff + vdk) * Sc + vkv;

  float nm = 0.f;       // nm = -mrow for q-row l15 (x4 replicated)
  f32x4 xacc[4] = {};   // out rows lhi*4+jj, cols dt*16+l15
  f32x4 lsum = {};      // row sums for rows lhi*4+jj (ones-MFMA)
  const int swzK = (l15 & 7) << 4;

  bf16x4 ones4;
#pragma unroll
  for (int i = 0; i < 4; ++i) ones4[i] = (bf16_t)1.0f;

#define DSTAGE(bi, kv0_)                                                        \
  do {                                                                          \
    gload_lds16(kS + (size_t)(kv0_)*Dc, (char*)lK[bi] + t * 16);                \
    gload_lds16(kS + (size_t)((kv0_) + 64) * Dc, (char*)lK[bi] + 8192 + t * 16);\
    gload_lds16(vS + (kv0_), (char*)lVT[bi] + t * 16);                          \
    gload_lds16(vS + (size_t)32 * Sc + (kv0_), (char*)lVT[bi] + 8192 + t * 16); \
  } while (0)

  DSTAGE(0, 0);
  asm volatile("s_waitcnt vmcnt(0)" ::: "memory");
  __builtin_amdgcn_s_barrier();
  __builtin_amdgcn_sched_barrier(0);

  const int NT2 = Sc / 128; // 16
  for (int tt = 0; tt < NT2; ++tt) {
    const int cur = tt & 1;
    if (tt + 1 < NT2) DSTAGE(cur ^ 1, (tt + 1) * 128);

    const char* K_ = (const char*)lK[cur];
    const char* VT_ = (const char*)lVT[cur];

    // swapped QK^T, rebased: sacc = S - mrow via MFMA C-init = -mrow.
    f32x4 nm4 = {nm, nm, nm, nm};
    f32x4 sacc[2][4];
    __builtin_amdgcn_s_setprio(1);
#pragma unroll
    for (int s64 = 0; s64 < 2; ++s64)
#pragma unroll
      for (int ct = 0; ct < 4; ++ct) {
        f32x4 z = nm4;
#pragma unroll
        for (int kk = 0; kk < 2; ++kk) {
          bf16x8 kf = *reinterpret_cast<const bf16x8*>(
              K_ + (((s64 * 64 + ct * 16 + l15) * 128 + kk * 64 + lhi * 16) ^ swzK));
          z = __builtin_amdgcn_mfma_f32_16x16x32_bf16(kf, qf[kk], z, 0, 0, 0);
        }
        sacc[s64][ct] = z;
      }
    __builtin_amdgcn_s_setprio(0);

    float m0a = fmaxf(fmaxf(sacc[0][0][0], sacc[0][0][1]), fmaxf(sacc[0][0][2], sacc[0][0][3]));
    float m0b = fmaxf(fmaxf(sacc[0][1][0], sacc[0][1][1]), fmaxf(sacc[0][1][2], sacc[0][1][3]));
    float m0c = fmaxf(fmaxf(sacc[0][2][0], sacc[0][2][1]), fmaxf(sacc[0][2][2], sacc[0][2][3]));
    float m0d = fmaxf(fmaxf(sacc[0][3][0], sacc[0][3][1]), fmaxf(sacc[0][3][2], sacc[0][3][3]));
    float m1a = fmaxf(fmaxf(sacc[1][0][0], sacc[1][0][1]), fmaxf(sacc[1][0][2], sacc[1][0][3]));
    float m1b = fmaxf(fmaxf(sacc[1][1][0], sacc[1][1][1]), fmaxf(sacc[1][1][2], sacc[1][1][3]));
    float m1c = fmaxf(fmaxf(sacc[1][2][0], sacc[1][2][1]), fmaxf(sacc[1][2][2], sacc[1][2][3]));
    float m1d = fmaxf(fmaxf(sacc[1][3][0], sacc[1][3][1]), fmaxf(sacc[1][3][2], sacc[1][3][3]));
    float mt = fmaxf(fmaxf(fmaxf(m0a, m0b), fmaxf(m0c, m0d)),
                     fmaxf(fmaxf(m1a, m1b), fmaxf(m1c, m1d)));

    if (__any(mt > 8.0f)) {
      float mtr = fmaxf(mt, __shfl_xor(mt, 16));
      mtr = fmaxf(mtr, __shfl_xor(mtr, 32));
      float mte = fmaxf(mtr, 0.f);
      float corr = fexp2(-mte);
      nm -= mte;
#pragma unroll
      for (int jj = 0; jj < 4; ++jj) {
        float cO = __shfl(corr, lhi * 4 + jj);
        lsum[jj] *= cO;
#pragma unroll
        for (int dt = 0; dt < 4; ++dt) xacc[dt][jj] *= cO;
      }
#pragma unroll
      for (int s64 = 0; s64 < 2; ++s64)
#pragma unroll
        for (int ct = 0; ct < 4; ++ct)
#pragma unroll
          for (int jj = 0; jj < 4; ++jj) sacc[s64][ct][jj] -= mte;
    }

    __builtin_amdgcn_s_setprio(1);
#pragma unroll
    for (int s64 = 0; s64 < 2; ++s64) {
      bf16x4 pa[4];
#pragma unroll
      for (int ct = 0; ct < 4; ++ct)
#pragma unroll
        for (int jj = 0; jj < 4; ++jj)
          pa[ct][jj] = (bf16_t)fexp2(sacc[s64][ct][jj]);
#pragma unroll
      for (int ct = 0; ct < 4; ++ct) lsum = mfma16(pa[ct], ones4, lsum);
#pragma unroll
      for (int dt = 0; dt < 4; ++dt) {
#pragma unroll
        for (int sel = 0; sel < 2; ++sel) {
          bf16x8 vb2 = *reinterpret_cast<const bf16x8*>(
              VT_ + (((dt * 16 + l15) * 256 + s64 * 128 + lhi * 32 + sel * 16) ^ swzK));
          bf16x4 vlo = __builtin_shufflevector(vb2, vb2, 0, 1, 2, 3);
          bf16x4 vhi = __builtin_shufflevector(vb2, vb2, 4, 5, 6, 7);
          xacc[dt] = mfma16(pa[2 * sel + 0], vlo, xacc[dt]);
          xacc[dt] = mfma16(pa[2 * sel + 1], vhi, xacc[dt]);
        }
      }
    }
    __builtin_amdgcn_s_setprio(0);

    asm volatile("s_waitcnt vmcnt(0)" ::: "memory");
    __builtin_amdgcn_s_barrier();
    __builtin_amdgcn_sched_barrier(0);
  }
#undef DSTAGE

  float iO[4];
#pragma unroll
  for (int jj = 0; jj < 4; ++jj) iO[jj] = 1.0f / lsum[jj];

  unsigned short* xp = X + base + (size_t)(q0 + wv * 16) * Dc + hoff;
#pragma unroll
  for (int dt = 0; dt < 4; ++dt)
#pragma unroll
    for (int jj = 0; jj < 4; ++jj) {
      int r = lhi * 4 + jj;
      xp[(size_t)r * Dc + dt * 16 + l15] = f2bf(xacc[dt][jj] * iO[jj]);
    }
}

// ---------------- launch ----------------
extern "C" void kernel_launch(void* const* d_in, const int* in_sizes, int n_in,
                              void* d_out, int out_size, void* d_ws, size_t ws_size,
                              hipStream_t stream) {
  const float* query = (const float*)d_in[0];
  const float* key   = (const float*)d_in[1];
  const float* value = (const float*)d_in[2];
  const float* Wq = (const float*)d_in[3];
  const float* bq = (const float*)d_in[4];
  const float* Wk = (const float*)d_in[5];
  const float* bk = (const float*)d_in[6];
  const float* Wv = (const float*)d_in[7];
  const float* bv = (const float*)d_in[8];
  const float* Wo = (const float*)d_in[9];
  const float* bo = (const float*)d_in[10];

  const size_t NBS = (size_t)Mrows * Dc; // 8388608
  const size_t NW  = (size_t)Dc * Dc;    // 1048576
  unsigned short* bWq  = (unsigned short*)d_ws;
  unsigned short* bWk  = bWq + NW;
  unsigned short* bWv  = bWk + NW;
  unsigned short* bWo  = bWv + NW;
  unsigned short* Qp   = bWo + NW;
  unsigned short* Kp   = Qp + NBS;
  unsigned short* Vtp  = Kp + NBS; // V projection, TRANSPOSED + field-swapped
  unsigned short* Xp   = Vtp + NBS;

  // weights: 4 contiguous segments (bWq..bWo); lg = log2(NW/4) = 18
  // (input fp32->bf16 cvt is fused into the QKV GEMM's A-staging)
  cvt_bf16_seg_kernel<<<(int)(4 * NW / 1024), 256, 0, stream>>>(
      Wq, Wk, Wv, Wo, bWq, 18);

  // fused Q/K/V projections, fp32-A: z selects; Q prescale folds 1/sqrt(DK)
  // AND log2(e) (attn softmax runs in exp2 domain)
  gemm_dbuf_kernel<true><<<dim3(Dc / 128, Mrows / 128, 3), 256, 0, stream>>>(
      query, key, value, bWq, bWk, bWv, bq, bk, bv, Qp, Kp, Vtp,
      Mrows, Dc, Dc, 0.125f * 1.44269504088896340736f);

  attn_kernel<<<dim3(Sc / 128, Hc, Bc), 512, 0, stream>>>(Qp, Kp, Vtp, Xp);

  gemm_dbuf_kernel<false><<<dim3(Dc / 128, Mrows / 128, 1), 256, 0, stream>>>(
      Xp, nullptr, nullptr, bWo, nullptr, nullptr, bo, nullptr, nullptr,
      d_out, nullptr, nullptr, Mrows, Dc, Dc, 1.0f);
}